// Round 5
// baseline (2208.936 us; speedup 1.0000x reference)
//
#include <hip/hip_runtime.h>
#include <cfloat>
#include <cmath>

#define TPB 256

typedef _Float16 half8 __attribute__((ext_vector_type(8)));
typedef float floatx16 __attribute__((ext_vector_type(16)));
typedef float floatx4 __attribute__((ext_vector_type(4)));

__device__ __forceinline__ float wave_reduce_sum(float v) {
#pragma unroll
  for (int off = 32; off > 0; off >>= 1) v += __shfl_xor(v, off, 64);
  return v;
}

// ---------------------------------------------------------------------------
// Kernel 0a: encoder conv2 B-fragments (2-part f16 split).
// ---------------------------------------------------------------------------
__global__ __launch_bounds__(64) void prep_bfrags(
    const float* __restrict__ ce_w2, const float* __restrict__ ge_w2,
    float* __restrict__ frags) {
  const int blk = blockIdx.x;  // 144 = 2 enc x 72 frags
  const int enc = blk / 72;
  const int frag = blk % 72;
  const int ks = frag >> 2, part = (frag >> 1) & 1, nt = frag & 1;
  const int tap = ks >> 1, half = ks & 1;
  const int lane = threadIdx.x;
  const float* w2 = enc ? ge_w2 : ce_w2;
  const int n = nt * 32 + (lane & 31);
  const int cb = half * 16 + (lane >> 5) * 8;
  half8 out;
#pragma unroll
  for (int j = 0; j < 8; ++j) {
    float v = w2[(n * 32 + cb + j) * 9 + tap];
    _Float16 h = (_Float16)v;
    out[j] = (part == 0) ? h : (_Float16)((v - (float)h) * 4096.f);
  }
  *(half8*)((char*)frags + ((size_t)blk * 64 + lane) * 16) = out;
}

// ---------------------------------------------------------------------------
// Kernel 0b: decoder deconv1 B-fragments (single f16).
// ---------------------------------------------------------------------------
__global__ __launch_bounds__(64) void prep_dec1(
    const float* __restrict__ w1, float* __restrict__ frags) {
  const int blk = blockIdx.x;
  const int phase = blk >> 4, ks = blk & 15;
  const int pa = phase >> 1, pb = phase & 1;
  const int st = ks >> 2, kk = ks & 3;
  const int s = st >> 1, tt = st & 1;
  const int lane = threadIdx.x;
  const int kg = lane >> 5, n = lane & 31;
  const int tap = (pa + 2 * s) * 4 + (pb + 2 * tt);
  half8 o;
#pragma unroll
  for (int j = 0; j < 8; ++j) {
    int c = kk * 16 + kg * 8 + j;
    o[j] = (_Float16)w1[tap * 2048 + c * 32 + n];
  }
  *(half8*)((char*)frags + ((size_t)blk * 64 + lane) * 16) = o;
}

// ---------------------------------------------------------------------------
// Kernel 0c: decfc B-fragments (f16).
// ---------------------------------------------------------------------------
__global__ __launch_bounds__(64) void prep_dfc(
    const float* __restrict__ dfcw, float* __restrict__ frags) {
  const int blk = blockIdx.x;  // 784 = 98 nt x 8 ks
  const int nt = blk >> 3, ks = blk & 7;
  const int lane = threadIdx.x;
  const int n = lane & 31, kg = lane >> 5;
  const int j = nt * 32 + n;
  const int px = j >> 6, c = j & 63;
  half8 o;
#pragma unroll
  for (int u = 0; u < 8; ++u)
    o[u] = (_Float16)dfcw[(size_t)(c * 49 + px) * 128 + ks * 16 + kg * 8 + u];
  *(half8*)((char*)frags + ((size_t)blk * 64 + lane) * 16) = o;
}

// ---------------------------------------------------------------------------
// Kernel 0d: mem B-fragments for match (2-part f16 split).
// ---------------------------------------------------------------------------
__global__ __launch_bounds__(64) void prep_mem(
    const float* __restrict__ memg, float* __restrict__ frags) {
  const int blk = blockIdx.x;  // 4096 = 256 tiles x 16 slots
  const int slot = blk & 15;
  const int p = slot >> 3, ks = slot & 7;
  const int T = blk >> 4;
  const int lane = threadIdx.x;
  const int n = lane & 31, kg = lane >> 5;
  const float* src = memg + (size_t)(T * 32 + n) * 128 + ks * 16 + kg * 8;
  half8 o;
#pragma unroll
  for (int j = 0; j < 8; ++j) {
    float v = src[j];
    _Float16 h = (_Float16)v;
    o[j] = p ? (_Float16)((v - (float)h) * 4096.f) : h;
  }
  *(half8*)((char*)frags + ((size_t)blk * 64 + lane) * 16) = o;
}

// ---------------------------------------------------------------------------
// Kernel 1: memory row inverse norms
// ---------------------------------------------------------------------------
__global__ __launch_bounds__(256) void norm_kernel(
    const float* __restrict__ memg, float* __restrict__ invn) {
  const int wv = threadIdx.x >> 6, lane = threadIdx.x & 63;
  const int row = blockIdx.x * 4 + wv;
  const float* r = memg + (size_t)row * 128;
  float a = r[lane], b = r[lane + 64];
  float s = wave_reduce_sum(a * a + b * b);
  if (lane == 0) invn[row] = 1.f / fmaxf(sqrtf(s), 1e-12f);
}

// ---------------------------------------------------------------------------
// Kernel 2: MFMA encoder v6 = v4 structure + software-pipelined inner loop.
// Bands of 7 rows, 4 blocks/CU, unit = (tile, both nt). The ks=0..17
// tap-half loop is fully unrolled as a ping-pong: next iteration's A (LDS)
// and B (global, L2) loads are issued BEFORE the current 6-MFMA cluster, so
// each load has ~192 cyc of MFMA to land under (covers L2 ~200cy latency).
// s_setprio(1) around MFMA clusters (blocks are phase-desynced).
// ---------------------------------------------------------------------------
#define ENC_OFFT(ks) \
  (((((ks) >> 1) / 3) * SP + (((ks) >> 1) % 3)) * 16 + \
   (((ks) & 1) ? 2 * GSTB : 0))
#define ENC_LOADK(P, ks)                                        \
  {                                                             \
    P##ah = *(const half8*)(Abase + ENC_OFFT(ks));              \
    P##al = *(const half8*)(Abase + PSTB + ENC_OFFT(ks));       \
    const char* bp_ = bgbase + (ks) * 4096;                     \
    P##bh0 = *(const half8*)(bp_);                              \
    P##bl0 = *(const half8*)(bp_ + 2048);                       \
    P##bh1 = *(const half8*)(bp_ + 1024);                       \
    P##bl1 = *(const half8*)(bp_ + 3072);                       \
  }
#define ENC_MFMAK(P)                                                           \
  {                                                                            \
    aH0 = __builtin_amdgcn_mfma_f32_32x32x16_f16(P##ah, P##bh0, aH0, 0, 0, 0); \
    aL0 = __builtin_amdgcn_mfma_f32_32x32x16_f16(P##ah, P##bl0, aL0, 0, 0, 0); \
    aL0 = __builtin_amdgcn_mfma_f32_32x32x16_f16(P##al, P##bh0, aL0, 0, 0, 0); \
    aH1 = __builtin_amdgcn_mfma_f32_32x32x16_f16(P##ah, P##bh1, aH1, 0, 0, 0); \
    aL1 = __builtin_amdgcn_mfma_f32_32x32x16_f16(P##ah, P##bl1, aL1, 0, 0, 0); \
    aL1 = __builtin_amdgcn_mfma_f32_32x32x16_f16(P##al, P##bh1, aL1, 0, 0, 0); \
  }

template <int S, bool CENTER>
__device__ __forceinline__ void encoder_body(
    char* smem, const float* __restrict__ x, const float* __restrict__ w1,
    const float* __restrict__ b1, const float* __restrict__ b2,
    const float* __restrict__ fcw, const float* __restrict__ fcb,
    const float* __restrict__ bfrag, float* __restrict__ zout, int zoff,
    int b) {
  constexpr int SP = S + 2;
  constexpr int NBANDS = S / 7;      // 4 (global) or 2 (center)
  constexpr int NPIX = 9 * SP;       // 7 output rows + 2 halo
  constexpr int GSTB = NPIX * 16;
  constexpr int PSTB = 4 * GSTB;
  constexpr int LIMIT = 7 * S;       // pixels per band
  constexpr int MTB = (LIMIT + 31) / 32;

  char* h1s = smem;
  float* xs = (float*)(smem + 2 * PSTB);
  float* w1s = xs + SP * SP;
  float* featp = w1s + 288;  // [4][64]

  const int t = threadIdx.x;
  const int lane = t & 63;
  const int wv = t >> 6;

  for (int e = t; e < SP * SP; e += TPB) xs[e] = 0.f;
  for (int e = t; e < 288; e += TPB) w1s[e] = w1[e];
  __syncthreads();
  const float* xb = x + (size_t)b * 784 + (CENTER ? (7 * 28 + 7) : 0);
  for (int e = t; e < S * S; e += TPB) {
    int i = e / S, j = e - i * S;
    xs[(i + 1) * SP + (j + 1)] = xb[i * 28 + j];
  }

  float sp0 = 0.f, sp1 = 0.f;
  const float bias0 = b2[lane & 31];
  const float bias1 = b2[32 + (lane & 31)];
  const int gOff = (lane >> 5) * GSTB;
  const char* bgbase = (const char*)bfrag + lane * 16;

#pragma unroll 1
  for (int band = 0; band < NBANDS; ++band) {
    const int b0 = band * 7;

    __syncthreads();
    for (int e = t; e < 4 * NPIX; e += TPB) {
      int g = e / NPIX;
      int pix = e - g * NPIX;
      int lr = pix / SP;
      int cw = pix - lr * SP;
      int gr = b0 - 1 + lr;
      int ebase = g * GSTB + pix * 16;
      half8 hi8 = {}, lo8 = {};
      if (gr >= 0 && gr < S && cw >= 1 && cw <= S) {
        float xv[9];
#pragma unroll
        for (int di = 0; di < 3; ++di)
#pragma unroll
          for (int dj = 0; dj < 3; ++dj)
            xv[di * 3 + dj] = xs[(gr + di) * SP + (cw - 1 + dj)];
#pragma unroll
        for (int u = 0; u < 8; ++u) {
          int ch = g * 8 + u;
          float a = b1[ch];
#pragma unroll
          for (int v = 0; v < 9; ++v) a += xv[v] * w1s[ch * 9 + v];
          a = fmaxf(a, 0.f);
          _Float16 h = (_Float16)a;
          hi8[u] = h;
          lo8[u] = (_Float16)((a - (float)h) * 4096.f);
        }
      }
      *(half8*)(h1s + ebase) = hi8;
      *(half8*)(h1s + PSTB + ebase) = lo8;
    }
    __syncthreads();
    // MFMA: unit = (single M-tile, both nt); ping-pong prefetch over ks=0..17
#pragma unroll 1
    for (int mt = wv; mt < MTB; mt += 4) {
      floatx16 aH0 = {}, aL0 = {}, aH1 = {}, aL1 = {};
      int px = mt * 32 + (lane & 31);
      px = px < LIMIT ? px : LIMIT - 1;
      const int r = px / S, cc = px - r * S;
      const char* Abase = h1s + (r * SP + cc) * 16 + gOff;

      half8 cah, cal, cbh0, cbl0, cbh1, cbl1;
      half8 nah, nal, nbh0, nbl0, nbh1, nbl1;
      ENC_LOADK(c, 0);
#pragma unroll
      for (int k2 = 0; k2 < 9; ++k2) {
        ENC_LOADK(n, 2 * k2 + 1);
        __builtin_amdgcn_s_setprio(1);
        ENC_MFMAK(c);
        __builtin_amdgcn_s_setprio(0);
        if (k2 < 8) ENC_LOADK(c, 2 * k2 + 2);
        __builtin_amdgcn_s_setprio(1);
        ENC_MFMAK(n);
        __builtin_amdgcn_s_setprio(0);
      }
#pragma unroll
      for (int reg = 0; reg < 16; ++reg) {
        int row = (reg & 3) + 8 * (reg >> 2) + 4 * (lane >> 5);
        int p = mt * 32 + row;
        if (p < LIMIT) {
          sp0 += fmaxf(aH0[reg] + aL0[reg] * (1.f / 4096.f) + bias0, 0.f);
          sp1 += fmaxf(aH1[reg] + aL1[reg] * (1.f / 4096.f) + bias1, 0.f);
        }
      }
    }
  }
  sp0 += __shfl_xor(sp0, 32);
  sp1 += __shfl_xor(sp1, 32);
  if (lane < 32) {
    featp[wv * 64 + lane] = sp0;
    featp[wv * 64 + 32 + lane] = sp1;
  }
  __syncthreads();
  if (t < 64)
    featp[t] = (featp[t] + featp[64 + t] + featp[128 + t] + featp[192 + t]) *
               (1.f / (S * S));
  __syncthreads();
  if (t < 64) {
    float s = 0.f;
#pragma unroll
    for (int i = 0; i < 64; ++i) s += featp[i] * fcw[t * 64 + i];
    zout[(size_t)b * 128 + zoff + t] = s + fcb[t];
  }
}

__global__ __launch_bounds__(256, 4) void encoders_fused(
    const float* __restrict__ x, const float* __restrict__ ce_w1,
    const float* __restrict__ ce_b1, const float* __restrict__ ce_b2,
    const float* __restrict__ ce_fcw, const float* __restrict__ ce_fcb,
    const float* __restrict__ ge_w1, const float* __restrict__ ge_b1,
    const float* __restrict__ ge_b2, const float* __restrict__ ge_fcw,
    const float* __restrict__ ge_fcb, const float* __restrict__ frags,
    float* __restrict__ z) {
  // S=28: 2*PSTB(34560) + xs(3600) + w1s(1152) + featp(1024) = 40336 -> 4/CU
  __shared__ __align__(16) char smem[40336];
  if (blockIdx.x < 2048)
    encoder_body<28, false>(smem, x, ge_w1, ge_b1, ge_b2, ge_fcw, ge_fcb,
                            frags + 18432, z, 64, blockIdx.x);
  else
    encoder_body<14, true>(smem, x, ce_w1, ce_b1, ce_b2, ce_fcw, ce_fcb, frags,
                           z, 0, blockIdx.x - 2048);
}

// ---------------------------------------------------------------------------
// Kernel 3a: match via split-f16 MFMA.
// ---------------------------------------------------------------------------
__global__ __launch_bounds__(256) void match_mfma(
    const float* __restrict__ z, const float* __restrict__ memfrags,
    const float* __restrict__ invn, float* __restrict__ topvw,
    int* __restrict__ topiw) {
  __shared__ __align__(16) char smem[49408];
  float* zs = (float*)smem;            // [32][128] fp32 (staging)
  float* qv = (float*)smem;            // [32][128] (after zs dead)
  int* qi = (int*)(smem + 16384);      // [32][128]
  char* zfrag = smem + 32768;          // 16 KB: [p][ks][kg*32+m][16B]
  float* rowmin = (float*)(smem + 49152);
  int* qn = (int*)(smem + 49152 + 128);

  const int t = threadIdx.x;
  const int lane = t & 63;
  const int wv = t >> 6;
  const int rowbase = blockIdx.x * 32;
  const int Tbase = blockIdx.y * 16;

  for (int e = t; e < 4096; e += TPB) zs[e] = z[(size_t)rowbase * 128 + e];
  if (t < 32) { rowmin[t] = -FLT_MAX; qn[t] = 0; }
  __syncthreads();
#pragma unroll
  for (int h = 0; h < 8; ++h) {
    int r = wv * 8 + h;
    float a = zs[r * 128 + lane], b = zs[r * 128 + 64 + lane];
    float s = wave_reduce_sum(a * a + b * b);
    float inv = 1.f / fmaxf(sqrtf(s), 1e-12f);
    zs[r * 128 + lane] = a * inv;
    zs[r * 128 + 64 + lane] = b * inv;
  }
  __syncthreads();
  // build z A-fragments (2-part split), frag-major: entry (ks*64+kg*32+m)
  for (int e = t; e < 4096; e += TPB) {
    int m = e >> 7, c = e & 127;
    float v = zs[m * 128 + c];
    _Float16 h = (_Float16)v;
    _Float16 l = (_Float16)((v - (float)h) * 4096.f);
    int ks = c >> 4, kg = (c >> 3) & 1, j = c & 7;
    int off = (ks * 64 + kg * 32 + m) * 16 + j * 2;
    *(_Float16*)(zfrag + off) = h;
    *(_Float16*)(zfrag + 8192 + off) = l;
  }
  __syncthreads();

  // hoist A-fragments to registers (constant across all 16 n-tiles)
  half8 ah[8], al[8];
  {
    const char* zf = zfrag + ((lane >> 5) * 32 + (lane & 31)) * 16;
#pragma unroll
    for (int ks = 0; ks < 8; ++ks) {
      ah[ks] = *(const half8*)(zf + ks * 1024);
      al[ks] = *(const half8*)(zf + 8192 + ks * 1024);
    }
  }

  float av[10];
  int ai[10];
#pragma unroll
  for (int i = 0; i < 10; ++i) { av[i] = -FLT_MAX; ai[i] = 0; }

#pragma unroll 1
  for (int round = 0; round < 4; ++round) {
    const int T = Tbase + round * 4 + wv;
    const char* bf = (const char*)memfrags + (size_t)T * 16384 + lane * 16;
    floatx16 acc0 = {}, acc1 = {};
#pragma unroll
    for (int ks = 0; ks < 8; ++ks) {
      half8 bh = *(const half8*)(bf + ks * 1024);
      half8 bl = *(const half8*)(bf + 8192 + ks * 1024);
      acc0 = __builtin_amdgcn_mfma_f32_32x32x16_f16(ah[ks], bh, acc0, 0, 0, 0);
      acc1 = __builtin_amdgcn_mfma_f32_32x32x16_f16(ah[ks], bl, acc1, 0, 0, 0);
      acc1 = __builtin_amdgcn_mfma_f32_32x32x16_f16(al[ks], bh, acc1, 0, 0, 0);
    }
    const int gn = T * 32 + (lane & 31);
    const float iv = invn[gn];
#pragma unroll
    for (int reg = 0; reg < 16; ++reg) {
      int m = (reg & 3) + 8 * (reg >> 2) + 4 * (lane >> 5);
      float v = (acc0[reg] + acc1[reg] * (1.f / 4096.f)) * iv;
      if (v > rowmin[m]) {
        int k = atomicAdd(&qn[m], 1);
        qv[m * 128 + k] = v;
        qi[m * 128 + k] = gn;
      }
    }
    __syncthreads();
    if (t < 32) {
      int n = qn[t];
      for (int k = 0; k < n; ++k) {
        float v = qv[t * 128 + k];
        int mm = qi[t * 128 + k];
        if (v > av[9]) {
#pragma unroll
          for (int i = 0; i < 10; ++i) {
            if (v > av[i]) {
              float tv = av[i]; av[i] = v; v = tv;
              int ti = ai[i]; ai[i] = mm; mm = ti;
            }
          }
        }
      }
      qn[t] = 0;
      rowmin[t] = av[9];
    }
    __syncthreads();
  }

  if (t < 32) {
    const size_t base = (size_t)(rowbase + t) * 160 + blockIdx.y * 10;
#pragma unroll
    for (int k = 0; k < 10; ++k) {
      topvw[base + k] = av[k];
      topiw[base + k] = ai[k];
    }
  }
}

// ---------------------------------------------------------------------------
// Kernel 3b: merge 16x10 candidates -> exact top-10 -> softmax -> blend (f16).
// ---------------------------------------------------------------------------
__global__ __launch_bounds__(256) void match_merge(
    const float* __restrict__ topvw, const int* __restrict__ topiw,
    const float* __restrict__ memg, _Float16* __restrict__ zmf16) {
  __shared__ float topw[8][10];
  __shared__ int topidx[8][10];
  const int t = threadIdx.x;
  const int rowbase = blockIdx.x * 8;

  if (t < 8) {
    float av[10];
    int ai[10];
#pragma unroll
    for (int i = 0; i < 10; ++i) { av[i] = -FLT_MAX; ai[i] = 0; }
    const size_t base = (size_t)(rowbase + t) * 160;
    for (int c = 0; c < 160; ++c) {
      float v = topvw[base + c];
      int m = topiw[base + c];
      if (v > av[9]) {
#pragma unroll
        for (int i = 0; i < 10; ++i) {
          if (v > av[i]) {
            float tv = av[i]; av[i] = v; v = tv;
            int ti = ai[i]; ai[i] = m; m = ti;
          }
        }
      }
    }
    float e_[10], s = 0.f;
#pragma unroll
    for (int k = 0; k < 10; ++k) { e_[k] = expf(av[k]); s += e_[k]; }
    float inv = 1.f / s;
#pragma unroll
    for (int k = 0; k < 10; ++k) { topw[t][k] = e_[k] * inv; topidx[t][k] = ai[k]; }
  }
  __syncthreads();
  for (int e = t; e < 8 * 128; e += TPB) {
    int r = e >> 7, d = e & 127;
    float o = 0.f;
#pragma unroll
    for (int k = 0; k < 10; ++k)
      o += topw[r][k] * memg[(size_t)topidx[r][k] * 128 + d];
    zmf16[(size_t)(rowbase + r) * 128 + d] = (_Float16)o;
  }
}

// ---------------------------------------------------------------------------
// Kernel 4: decoder FC via f16 MFMA.
// ---------------------------------------------------------------------------
__global__ __launch_bounds__(256) void decfc_kernel(
    const _Float16* __restrict__ zmf16, const float* __restrict__ fcb,
    const float* __restrict__ dfcfrags, _Float16* __restrict__ d0f16) {
  const int t = threadIdx.x;
  const int lane = t & 63;
  const int wv = t >> 6;
  const int r0 = blockIdx.x * 32;
  const int ntbase = blockIdx.y * 49;

  half8 a[8];
  {
    const _Float16* ap =
        zmf16 + (size_t)(r0 + (lane & 31)) * 128 + (lane >> 5) * 8;
#pragma unroll
    for (int ks = 0; ks < 8; ++ks) a[ks] = *(const half8*)(ap + ks * 16);
  }
  const char* fb = (const char*)dfcfrags + lane * 16;

  for (int nt = ntbase + wv; nt < ntbase + 49; nt += 4) {
    half8 bfr[8];
    const char* p = fb + (size_t)nt * 8192;
#pragma unroll
    for (int ks = 0; ks < 8; ++ks) bfr[ks] = *(const half8*)(p + ks * 1024);
    floatx16 acc = {};
#pragma unroll
    for (int ks = 0; ks < 8; ++ks)
      acc = __builtin_amdgcn_mfma_f32_32x32x16_f16(a[ks], bfr[ks], acc, 0, 0, 0);
    const int col = nt * 32 + (lane & 31);
    const int px = col >> 6, c = col & 63;
    const float bias = fcb[c * 49 + px];
#pragma unroll
    for (int reg = 0; reg < 16; ++reg) {
      int row = (reg & 3) + 8 * (reg >> 2) + 4 * (lane >> 5);
      d0f16[((size_t)(r0 + row) * 49 + px) * 64 + c] = (_Float16)(acc[reg] + bias);
    }
  }
}

// ---------------------------------------------------------------------------
// Kernel 5: decoder v4 — deconv1 + conv2 via f16 MFMA.
// ---------------------------------------------------------------------------
__global__ __launch_bounds__(256) void decoder_kernel(
    const _Float16* __restrict__ d0f16, const float* __restrict__ b1,
    const float* __restrict__ w2, const float* __restrict__ b2,
    const float* __restrict__ w3, const float* __restrict__ b3,
    const float* __restrict__ w4, const float* __restrict__ b4,
    const float* __restrict__ dec1frags, float* __restrict__ out) {
  __shared__ __align__(16) char dsm[41408];
  char* d0f = dsm;
  float* d2 = (float*)dsm;
  char* d1f = dsm + 12608;
  char* w2s = dsm + 28992;
  float* d3 = (float*)(dsm + 12608);

  const int b = blockIdx.x;
  const int t = threadIdx.x;
  const int lane = t & 63;
  const int wv = t >> 6;

  for (int e = t; e < 648; e += TPB) {
    int g = e / 81, pix = e - g * 81;
    int ih = pix / 9 - 1, iw = pix % 9 - 1;
    half8 hv = {};
    if (ih >= 0 && ih < 7 && iw >= 0 && iw < 7)
      hv = *(const half8*)(d0f16 + ((size_t)b * 49 + ih * 7 + iw) * 64 + g * 8);
    *(half8*)(d0f + e * 16) = hv;
  }
  for (int e = t; e < 576; e += TPB) {
    int tau = e / 64, l = e - tau * 64;
    int n = l & 15, kq = l >> 4;
    half8 v;
#pragma unroll
    for (int u = 0; u < 8; ++u)
      v[u] = (_Float16)w2[(n * 32 + kq * 8 + u) * 9 + tau];
    *(half8*)(w2s + e * 16) = v;
  }
  for (int e = t; e < 1024; e += TPB)
    *(float4*)(d1f + e * 16) = make_float4(0.f, 0.f, 0.f, 0.f);
  __syncthreads();

  {
    const int pa = wv >> 1, pb = wv & 1;
    const int kg = lane >> 5, o = lane & 31;
    const char* bg = (const char*)dec1frags + wv * 16384 + lane * 16;
    int pxa[2][4];
#pragma unroll
    for (int im = 0; im < 2; ++im) {
      int px = im * 32 + o;
      px = px < 49 ? px : 48;
      int i = px / 7, j2 = px - i * 7;
#pragma unroll
      for (int st = 0; st < 4; ++st) {
        int s = st >> 1, tt = st & 1;
        pxa[im][st] = ((i + pa + s) * 9 + (j2 + pb + tt)) * 16;
      }
    }
    floatx16 acc0 = {}, acc1 = {};
    half8 nb = *(const half8*)(bg);
#pragma unroll
    for (int ks = 0; ks < 16; ++ks) {
      half8 bf = nb;
      if (ks < 15) nb = *(const half8*)(bg + (ks + 1) * 1024);
      const int gbase = (((ks & 3) * 2 + kg) * 81) * 16;
      half8 a0 = *(const half8*)(d0f + gbase + pxa[0][ks >> 2]);
      half8 a1 = *(const half8*)(d0f + gbase + pxa[1][ks >> 2]);
      acc0 = __builtin_amdgcn_mfma_f32_32x32x16_f16(a0, bf, acc0, 0, 0, 0);
      acc1 = __builtin_amdgcn_mfma_f32_32x32x16_f16(a1, bf, acc1, 0, 0, 0);
    }
    const float bias = b1[o];
    char* dst = d1f + (o >> 3) * 4096 + (o & 7) * 2;
#pragma unroll
    for (int im = 0; im < 2; ++im) {
      const floatx16& ac = im ? acc1 : acc0;
#pragma unroll
      for (int reg = 0; reg < 16; ++reg) {
        int row = (reg & 3) + 8 * (reg >> 2) + 4 * kg;
        int px = im * 32 + row;
        if (px < 49) {
          int i = px / 7, j2 = px - i * 7;
          int p = 2 * i + pa, q = 2 * j2 + pb;
          *(_Float16*)(dst + ((p + 1) * 16 + (q + 1)) * 16) =
              (_Float16)fmaxf(ac[reg] + bias, 0.f);
        }
      }
    }
  }
  __syncthreads();

  {
    const int m = lane & 15, kq = lane >> 4;
    half8 bq[9];
#pragma unroll
    for (int tau = 0; tau < 9; ++tau)
      bq[tau] = *(const half8*)(w2s + (tau * 64 + lane) * 16);
    for (int mt = wv; mt < 13; mt += 4) {
      int px = mt * 16 + m;
      px = px < 196 ? px : 195;
      const int p = px / 14, q = px - (px / 14) * 14;
      floatx4 acc = {};
#pragma unroll
      for (int tau = 0; tau < 9; ++tau) {
        const int dp = tau / 3, dq = tau - dp * 3;
        half8 av =
            *(const half8*)(d1f + (kq * 256 + (p + dp) * 16 + (q + dq)) * 16);
        acc = __builtin_amdgcn_mfma_f32_16x16x32_f16(av, bq[tau], acc, 0, 0, 0);
      }
      const int o = lane & 15;
      const float bias = b2[o];
#pragma unroll
      for (int reg = 0; reg < 4; ++reg) {
        int row = (lane >> 4) * 4 + reg;
        int opx = mt * 16 + row;
        if (opx < 196) d2[o * 197 + opx] = fmaxf(acc[reg] + bias, 0.f);
      }
    }
  }
  __syncthreads();
  for (int e = t; e < 7200; e += TPB) d3[e] = 0.f;
  __syncthreads();

  {
    const int ph = __builtin_amdgcn_readfirstlane(t >> 6);
    const int pa = ph >> 1, pb = ph & 1;
    const int tb = pa * 4 + pb;
    const float* wA = w3 + (size_t)tb * 128;
    const float* wB = w3 + (size_t)(tb + 2) * 128;
    const float* wC = w3 + (size_t)(tb + 8) * 128;
    const float* wD = w3 + (size_t)(tb + 10) * 128;
#pragma unroll 1
    for (int k = 0; k < 4; ++k) {
      const int px = lane + 64 * k;
      const int cpx = px < 196 ? px : 195;
      const int i = cpx / 14, j = cpx % 14;
      int ih[2], iw[2];
      float mh[2], mw[2];
#pragma unroll
      for (int s = 0; s < 2; ++s) {
        int v = i + pa + s - 1;
        mh[s] = (v >= 0 && v <= 13) ? 1.f : 0.f;
        ih[s] = v < 0 ? 0 : (v > 13 ? 13 : v);
        int u = j + pb + s - 1;
        mw[s] = (u >= 0 && u <= 13) ? 1.f : 0.f;
        iw[s] = u < 0 ? 0 : (u > 13 ? 13 : u);
      }
      const float m00 = mh[0] * mw[0], m01 = mh[0] * mw[1];
      const float m10 = mh[1] * mw[0], m11 = mh[1] * mw[1];
      float acc[8];
#pragma unroll
      for (int oo = 0; oo < 8; ++oo) acc[oo] = b3[oo];
#pragma unroll 2
      for (int c = 0; c < 16; ++c) {
        const float a00 = d2[c * 197 + ih[0] * 14 + iw[0]] * m00;
        const float a01 = d2[c * 197 + ih[0] * 14 + iw[1]] * m01;
        const float a10 = d2[c * 197 + ih[1] * 14 + iw[0]] * m10;
        const float a11 = d2[c * 197 + ih[1] * 14 + iw[1]] * m11;
        const int wb = c * 8;
#pragma unroll
        for (int oo = 0; oo < 8; ++oo)
          acc[oo] += a00 * wA[wb + oo] + a01 * wB[wb + oo] +
                     a10 * wC[wb + oo] + a11 * wD[wb + oo];
      }
      if (px < 196) {
        const int p = 2 * i + pa, q = 2 * j + pb;
        const int widx = (p + 1) * 30 + (q + 1);
#pragma unroll
        for (int oo = 0; oo < 8; ++oo)
          d3[oo * 900 + widx] = fmaxf(acc[oo], 0.f);
      }
    }
  }
  __syncthreads();

  for (int e = t; e < 784; e += TPB) {
    int p = e / 28, q = e - p * 28;
    float a = b4[0];
#pragma unroll
    for (int c = 0; c < 8; ++c) {
      const float* bp = &d3[c * 900 + p * 30 + q];
#pragma unroll
      for (int di = 0; di < 3; ++di)
#pragma unroll
        for (int dj = 0; dj < 3; ++dj)
          a += bp[di * 30 + dj] * w4[c * 9 + di * 3 + dj];
    }
    out[(size_t)b * 784 + e] = a;
  }
}

// ---------------------------------------------------------------------------
extern "C" void kernel_launch(void* const* d_in, const int* in_sizes, int n_in,
                              void* d_out, int out_size, void* d_ws,
                              size_t ws_size, hipStream_t stream) {
  const float* x      = (const float*)d_in[0];
  const float* ce_w1  = (const float*)d_in[1];
  const float* ce_b1  = (const float*)d_in[2];
  const float* ce_w2  = (const float*)d_in[3];
  const float* ce_b2  = (const float*)d_in[4];
  const float* ce_fcw = (const float*)d_in[5];
  const float* ce_fcb = (const float*)d_in[6];
  const float* ge_w1  = (const float*)d_in[7];
  const float* ge_b1  = (const float*)d_in[8];
  const float* ge_w2  = (const float*)d_in[9];
  const float* ge_b2  = (const float*)d_in[10];
  const float* ge_fcw = (const float*)d_in[11];
  const float* ge_fcb = (const float*)d_in[12];
  const float* memg   = (const float*)d_in[13];
  const float* dfcw   = (const float*)d_in[14];
  const float* dfcb   = (const float*)d_in[15];
  const float* d_w1   = (const float*)d_in[16];
  const float* d_b1   = (const float*)d_in[17];
  const float* d_w2   = (const float*)d_in[18];
  const float* d_b2   = (const float*)d_in[19];
  const float* d_w3   = (const float*)d_in[20];
  const float* d_b3   = (const float*)d_in[21];
  const float* d_w4   = (const float*)d_in[22];
  const float* d_b4   = (const float*)d_in[23];
  float* outp = (float*)d_out;

  float*     ws        = (float*)d_ws;
  float*     z         = ws;
  _Float16*  zmf16     = (_Float16*)(ws + 262144);
  float*     invn      = ws + 262144 + 131072;
  float*     frags     = invn + 8192;
  float*     dec1frags = frags + 36864;
  float*     dfcfrags  = dec1frags + 16384;
  float*     memfrags  = dfcfrags + 200704;
  float*     tailbase  = memfrags + 1048576;
  float*     topvw     = tailbase;
  int*       topiw     = (int*)(tailbase + 327680);
  _Float16*  d0f16     = (_Float16*)tailbase;

  prep_bfrags<<<144, 64, 0, stream>>>(ce_w2, ge_w2, frags);
  prep_dec1<<<64, 64, 0, stream>>>(d_w1, dec1frags);
  prep_dfc<<<784, 64, 0, stream>>>(dfcw, dfcfrags);
  prep_mem<<<4096, 64, 0, stream>>>(memg, memfrags);
  norm_kernel<<<2048, TPB, 0, stream>>>(memg, invn);
  encoders_fused<<<4096, TPB, 0, stream>>>(x, ce_w1, ce_b1, ce_b2, ce_fcw,
                                           ce_fcb, ge_w1, ge_b1, ge_b2, ge_fcw,
                                           ge_fcb, frags, z);
  match_mfma<<<dim3(64, 16), TPB, 0, stream>>>(z, memfrags, invn, topvw, topiw);
  match_merge<<<256, TPB, 0, stream>>>(topvw, topiw, memg, zmf16);
  decfc_kernel<<<dim3(64, 2), TPB, 0, stream>>>(zmf16, dfcb, dfcfrags, d0f16);
  decoder_kernel<<<2048, TPB, 0, stream>>>(d0f16, d_b1, d_w2, d_b2, d_w3, d_b3,
                                           d_w4, d_b4, dec1frags, outp);
}

// Round 6
// 1887.962 us; speedup vs baseline: 1.1700x; 1.1700x over previous
//
#include <hip/hip_runtime.h>
#include <cfloat>
#include <cmath>

#define TPB 256

typedef _Float16 half8 __attribute__((ext_vector_type(8)));
typedef float floatx16 __attribute__((ext_vector_type(16)));
typedef float floatx4 __attribute__((ext_vector_type(4)));

__device__ __forceinline__ float wave_reduce_sum(float v) {
#pragma unroll
  for (int off = 32; off > 0; off >>= 1) v += __shfl_xor(v, off, 64);
  return v;
}

// ---------------------------------------------------------------------------
// Kernel 0a: encoder conv2 B-fragments (2-part f16 split).
// ---------------------------------------------------------------------------
__global__ __launch_bounds__(64) void prep_bfrags(
    const float* __restrict__ ce_w2, const float* __restrict__ ge_w2,
    float* __restrict__ frags) {
  const int blk = blockIdx.x;  // 144 = 2 enc x 72 frags
  const int enc = blk / 72;
  const int frag = blk % 72;
  const int ks = frag >> 2, part = (frag >> 1) & 1, nt = frag & 1;
  const int tap = ks >> 1, half = ks & 1;
  const int lane = threadIdx.x;
  const float* w2 = enc ? ge_w2 : ce_w2;
  const int n = nt * 32 + (lane & 31);
  const int cb = half * 16 + (lane >> 5) * 8;
  half8 out;
#pragma unroll
  for (int j = 0; j < 8; ++j) {
    float v = w2[(n * 32 + cb + j) * 9 + tap];
    _Float16 h = (_Float16)v;
    out[j] = (part == 0) ? h : (_Float16)((v - (float)h) * 4096.f);
  }
  *(half8*)((char*)frags + ((size_t)blk * 64 + lane) * 16) = out;
}

// ---------------------------------------------------------------------------
// Kernel 0b: decoder deconv1 B-fragments (single f16).
// ---------------------------------------------------------------------------
__global__ __launch_bounds__(64) void prep_dec1(
    const float* __restrict__ w1, float* __restrict__ frags) {
  const int blk = blockIdx.x;
  const int phase = blk >> 4, ks = blk & 15;
  const int pa = phase >> 1, pb = phase & 1;
  const int st = ks >> 2, kk = ks & 3;
  const int s = st >> 1, tt = st & 1;
  const int lane = threadIdx.x;
  const int kg = lane >> 5, n = lane & 31;
  const int tap = (pa + 2 * s) * 4 + (pb + 2 * tt);
  half8 o;
#pragma unroll
  for (int j = 0; j < 8; ++j) {
    int c = kk * 16 + kg * 8 + j;
    o[j] = (_Float16)w1[tap * 2048 + c * 32 + n];
  }
  *(half8*)((char*)frags + ((size_t)blk * 64 + lane) * 16) = o;
}

// ---------------------------------------------------------------------------
// Kernel 0c: decfc B-fragments (f16).
// ---------------------------------------------------------------------------
__global__ __launch_bounds__(64) void prep_dfc(
    const float* __restrict__ dfcw, float* __restrict__ frags) {
  const int blk = blockIdx.x;  // 784 = 98 nt x 8 ks
  const int nt = blk >> 3, ks = blk & 7;
  const int lane = threadIdx.x;
  const int n = lane & 31, kg = lane >> 5;
  const int j = nt * 32 + n;
  const int px = j >> 6, c = j & 63;
  half8 o;
#pragma unroll
  for (int u = 0; u < 8; ++u)
    o[u] = (_Float16)dfcw[(size_t)(c * 49 + px) * 128 + ks * 16 + kg * 8 + u];
  *(half8*)((char*)frags + ((size_t)blk * 64 + lane) * 16) = o;
}

// ---------------------------------------------------------------------------
// Kernel 0d: mem B-fragments for match (2-part f16 split).
// ---------------------------------------------------------------------------
__global__ __launch_bounds__(64) void prep_mem(
    const float* __restrict__ memg, float* __restrict__ frags) {
  const int blk = blockIdx.x;  // 4096 = 256 tiles x 16 slots
  const int slot = blk & 15;
  const int p = slot >> 3, ks = slot & 7;
  const int T = blk >> 4;
  const int lane = threadIdx.x;
  const int n = lane & 31, kg = lane >> 5;
  const float* src = memg + (size_t)(T * 32 + n) * 128 + ks * 16 + kg * 8;
  half8 o;
#pragma unroll
  for (int j = 0; j < 8; ++j) {
    float v = src[j];
    _Float16 h = (_Float16)v;
    o[j] = p ? (_Float16)((v - (float)h) * 4096.f) : h;
  }
  *(half8*)((char*)frags + ((size_t)blk * 64 + lane) * 16) = o;
}

// ---------------------------------------------------------------------------
// Kernel 1: memory row inverse norms
// ---------------------------------------------------------------------------
__global__ __launch_bounds__(256) void norm_kernel(
    const float* __restrict__ memg, float* __restrict__ invn) {
  const int wv = threadIdx.x >> 6, lane = threadIdx.x & 63;
  const int row = blockIdx.x * 4 + wv;
  const float* r = memg + (size_t)row * 128;
  float a = r[lane], b = r[lane + 64];
  float s = wave_reduce_sum(a * a + b * b);
  if (lane == 0) invn[row] = 1.f / fmaxf(sqrtf(s), 1e-12f);
}

// ---------------------------------------------------------------------------
// Kernel 2: MFMA encoder v7.
// v4 band structure (7-row bands, unit = (tile, both nt)). Register budget
// fix: unified VGPR+AGPR file means (256,4) = 128 regs/wave = 64 arch +
// 64 acc with ZERO headroom (v6's pipeline spilled 2.6GB). (256,3) = 170
// regs/wave -> room for a depth-1 B-prefetch ring (+16 VGPR): the next
// tap-half's B set (L2, ~200cy) is issued before the current 6-MFMA
// cluster. A stays JIT from LDS (~120cy lgkm, cheap). s_setprio(1) around
// MFMA clusters (blocks phase-desynced). 3 vs 4 blocks/CU is known-neutral
// (v3 == v4 == 308us).
// ---------------------------------------------------------------------------
template <int S, bool CENTER>
__device__ __forceinline__ void encoder_body(
    char* smem, const float* __restrict__ x, const float* __restrict__ w1,
    const float* __restrict__ b1, const float* __restrict__ b2,
    const float* __restrict__ fcw, const float* __restrict__ fcb,
    const float* __restrict__ bfrag, float* __restrict__ zout, int zoff,
    int b) {
  constexpr int SP = S + 2;
  constexpr int NBANDS = S / 7;      // 4 (global) or 2 (center)
  constexpr int NPIX = 9 * SP;       // 7 output rows + 2 halo
  constexpr int GSTB = NPIX * 16;
  constexpr int PSTB = 4 * GSTB;
  constexpr int LIMIT = 7 * S;       // pixels per band
  constexpr int MTB = (LIMIT + 31) / 32;

  char* h1s = smem;
  float* xs = (float*)(smem + 2 * PSTB);
  float* w1s = xs + SP * SP;
  float* featp = w1s + 288;  // [4][64]

  const int t = threadIdx.x;
  const int lane = t & 63;
  const int wv = t >> 6;

  for (int e = t; e < SP * SP; e += TPB) xs[e] = 0.f;
  for (int e = t; e < 288; e += TPB) w1s[e] = w1[e];
  __syncthreads();
  const float* xb = x + (size_t)b * 784 + (CENTER ? (7 * 28 + 7) : 0);
  for (int e = t; e < S * S; e += TPB) {
    int i = e / S, j = e - i * S;
    xs[(i + 1) * SP + (j + 1)] = xb[i * 28 + j];
  }

  float sp0 = 0.f, sp1 = 0.f;
  const float bias0 = b2[lane & 31];
  const float bias1 = b2[32 + (lane & 31)];
  const int gOff = (lane >> 5) * GSTB;
  const char* bgbase = (const char*)bfrag + lane * 16;

#pragma unroll 1
  for (int band = 0; band < NBANDS; ++band) {
    const int b0 = band * 7;

    __syncthreads();
    for (int e = t; e < 4 * NPIX; e += TPB) {
      int g = e / NPIX;
      int pix = e - g * NPIX;
      int lr = pix / SP;
      int cw = pix - lr * SP;
      int gr = b0 - 1 + lr;
      int ebase = g * GSTB + pix * 16;
      half8 hi8 = {}, lo8 = {};
      if (gr >= 0 && gr < S && cw >= 1 && cw <= S) {
        float xv[9];
#pragma unroll
        for (int di = 0; di < 3; ++di)
#pragma unroll
          for (int dj = 0; dj < 3; ++dj)
            xv[di * 3 + dj] = xs[(gr + di) * SP + (cw - 1 + dj)];
#pragma unroll
        for (int u = 0; u < 8; ++u) {
          int ch = g * 8 + u;
          float a = b1[ch];
#pragma unroll
          for (int v = 0; v < 9; ++v) a += xv[v] * w1s[ch * 9 + v];
          a = fmaxf(a, 0.f);
          _Float16 h = (_Float16)a;
          hi8[u] = h;
          lo8[u] = (_Float16)((a - (float)h) * 4096.f);
        }
      }
      *(half8*)(h1s + ebase) = hi8;
      *(half8*)(h1s + PSTB + ebase) = lo8;
    }
    __syncthreads();
    // MFMA: unit = (single M-tile, both nt); depth-1 B prefetch ring
#pragma unroll 1
    for (int mt = wv; mt < MTB; mt += 4) {
      floatx16 aH0 = {}, aL0 = {}, aH1 = {}, aL1 = {};
      int px = mt * 32 + (lane & 31);
      px = px < LIMIT ? px : LIMIT - 1;
      const int r = px / S, cc = px - r * S;
      const char* Abase = h1s + (r * SP + cc) * 16 + gOff;

      half8 bh0 = *(const half8*)(bgbase);
      half8 bl0 = *(const half8*)(bgbase + 2048);
      half8 bh1 = *(const half8*)(bgbase + 1024);
      half8 bl1 = *(const half8*)(bgbase + 3072);
#pragma unroll
      for (int ks = 0; ks < 18; ++ks) {
        const int tap = ks >> 1, di = tap / 3, dj = tap - di * 3;
        const int offA = (di * SP + dj) * 16 + ((ks & 1) ? 2 * GSTB : 0);
        half8 ah = *(const half8*)(Abase + offA);
        half8 al = *(const half8*)(Abase + PSTB + offA);
        // prefetch next B set (clamped; full unroll renames registers)
        const char* np = bgbase + (ks < 17 ? ks + 1 : 17) * 4096;
        half8 nbh0 = *(const half8*)(np);
        half8 nbl0 = *(const half8*)(np + 2048);
        half8 nbh1 = *(const half8*)(np + 1024);
        half8 nbl1 = *(const half8*)(np + 3072);
        __builtin_amdgcn_s_setprio(1);
        aH0 = __builtin_amdgcn_mfma_f32_32x32x16_f16(ah, bh0, aH0, 0, 0, 0);
        aL0 = __builtin_amdgcn_mfma_f32_32x32x16_f16(ah, bl0, aL0, 0, 0, 0);
        aL0 = __builtin_amdgcn_mfma_f32_32x32x16_f16(al, bh0, aL0, 0, 0, 0);
        aH1 = __builtin_amdgcn_mfma_f32_32x32x16_f16(ah, bh1, aH1, 0, 0, 0);
        aL1 = __builtin_amdgcn_mfma_f32_32x32x16_f16(ah, bl1, aL1, 0, 0, 0);
        aL1 = __builtin_amdgcn_mfma_f32_32x32x16_f16(al, bh1, aL1, 0, 0, 0);
        __builtin_amdgcn_s_setprio(0);
        bh0 = nbh0;
        bl0 = nbl0;
        bh1 = nbh1;
        bl1 = nbl1;
      }
#pragma unroll
      for (int reg = 0; reg < 16; ++reg) {
        int row = (reg & 3) + 8 * (reg >> 2) + 4 * (lane >> 5);
        int p = mt * 32 + row;
        if (p < LIMIT) {
          sp0 += fmaxf(aH0[reg] + aL0[reg] * (1.f / 4096.f) + bias0, 0.f);
          sp1 += fmaxf(aH1[reg] + aL1[reg] * (1.f / 4096.f) + bias1, 0.f);
        }
      }
    }
  }
  sp0 += __shfl_xor(sp0, 32);
  sp1 += __shfl_xor(sp1, 32);
  if (lane < 32) {
    featp[wv * 64 + lane] = sp0;
    featp[wv * 64 + 32 + lane] = sp1;
  }
  __syncthreads();
  if (t < 64)
    featp[t] = (featp[t] + featp[64 + t] + featp[128 + t] + featp[192 + t]) *
               (1.f / (S * S));
  __syncthreads();
  if (t < 64) {
    float s = 0.f;
#pragma unroll
    for (int i = 0; i < 64; ++i) s += featp[i] * fcw[t * 64 + i];
    zout[(size_t)b * 128 + zoff + t] = s + fcb[t];
  }
}

__global__ __launch_bounds__(256, 3) void encoders_fused(
    const float* __restrict__ x, const float* __restrict__ ce_w1,
    const float* __restrict__ ce_b1, const float* __restrict__ ce_b2,
    const float* __restrict__ ce_fcw, const float* __restrict__ ce_fcb,
    const float* __restrict__ ge_w1, const float* __restrict__ ge_b1,
    const float* __restrict__ ge_b2, const float* __restrict__ ge_fcw,
    const float* __restrict__ ge_fcb, const float* __restrict__ frags,
    float* __restrict__ z) {
  // S=28: 2*PSTB(34560) + xs(3600) + w1s(1152) + featp(1024) = 40336
  __shared__ __align__(16) char smem[40336];
  if (blockIdx.x < 2048)
    encoder_body<28, false>(smem, x, ge_w1, ge_b1, ge_b2, ge_fcw, ge_fcb,
                            frags + 18432, z, 64, blockIdx.x);
  else
    encoder_body<14, true>(smem, x, ce_w1, ce_b1, ce_b2, ce_fcw, ce_fcb, frags,
                           z, 0, blockIdx.x - 2048);
}

// ---------------------------------------------------------------------------
// Kernel 3a: match via split-f16 MFMA.
// ---------------------------------------------------------------------------
__global__ __launch_bounds__(256) void match_mfma(
    const float* __restrict__ z, const float* __restrict__ memfrags,
    const float* __restrict__ invn, float* __restrict__ topvw,
    int* __restrict__ topiw) {
  __shared__ __align__(16) char smem[49408];
  float* zs = (float*)smem;            // [32][128] fp32 (staging)
  float* qv = (float*)smem;            // [32][128] (after zs dead)
  int* qi = (int*)(smem + 16384);      // [32][128]
  char* zfrag = smem + 32768;          // 16 KB: [p][ks][kg*32+m][16B]
  float* rowmin = (float*)(smem + 49152);
  int* qn = (int*)(smem + 49152 + 128);

  const int t = threadIdx.x;
  const int lane = t & 63;
  const int wv = t >> 6;
  const int rowbase = blockIdx.x * 32;
  const int Tbase = blockIdx.y * 16;

  for (int e = t; e < 4096; e += TPB) zs[e] = z[(size_t)rowbase * 128 + e];
  if (t < 32) { rowmin[t] = -FLT_MAX; qn[t] = 0; }
  __syncthreads();
#pragma unroll
  for (int h = 0; h < 8; ++h) {
    int r = wv * 8 + h;
    float a = zs[r * 128 + lane], b = zs[r * 128 + 64 + lane];
    float s = wave_reduce_sum(a * a + b * b);
    float inv = 1.f / fmaxf(sqrtf(s), 1e-12f);
    zs[r * 128 + lane] = a * inv;
    zs[r * 128 + 64 + lane] = b * inv;
  }
  __syncthreads();
  // build z A-fragments (2-part split), frag-major: entry (ks*64+kg*32+m)
  for (int e = t; e < 4096; e += TPB) {
    int m = e >> 7, c = e & 127;
    float v = zs[m * 128 + c];
    _Float16 h = (_Float16)v;
    _Float16 l = (_Float16)((v - (float)h) * 4096.f);
    int ks = c >> 4, kg = (c >> 3) & 1, j = c & 7;
    int off = (ks * 64 + kg * 32 + m) * 16 + j * 2;
    *(_Float16*)(zfrag + off) = h;
    *(_Float16*)(zfrag + 8192 + off) = l;
  }
  __syncthreads();

  // hoist A-fragments to registers (constant across all 16 n-tiles)
  half8 ah[8], al[8];
  {
    const char* zf = zfrag + ((lane >> 5) * 32 + (lane & 31)) * 16;
#pragma unroll
    for (int ks = 0; ks < 8; ++ks) {
      ah[ks] = *(const half8*)(zf + ks * 1024);
      al[ks] = *(const half8*)(zf + 8192 + ks * 1024);
    }
  }

  float av[10];
  int ai[10];
#pragma unroll
  for (int i = 0; i < 10; ++i) { av[i] = -FLT_MAX; ai[i] = 0; }

#pragma unroll 1
  for (int round = 0; round < 4; ++round) {
    const int T = Tbase + round * 4 + wv;
    const char* bf = (const char*)memfrags + (size_t)T * 16384 + lane * 16;
    floatx16 acc0 = {}, acc1 = {};
#pragma unroll
    for (int ks = 0; ks < 8; ++ks) {
      half8 bh = *(const half8*)(bf + ks * 1024);
      half8 bl = *(const half8*)(bf + 8192 + ks * 1024);
      acc0 = __builtin_amdgcn_mfma_f32_32x32x16_f16(ah[ks], bh, acc0, 0, 0, 0);
      acc1 = __builtin_amdgcn_mfma_f32_32x32x16_f16(ah[ks], bl, acc1, 0, 0, 0);
      acc1 = __builtin_amdgcn_mfma_f32_32x32x16_f16(al[ks], bh, acc1, 0, 0, 0);
    }
    const int gn = T * 32 + (lane & 31);
    const float iv = invn[gn];
#pragma unroll
    for (int reg = 0; reg < 16; ++reg) {
      int m = (reg & 3) + 8 * (reg >> 2) + 4 * (lane >> 5);
      float v = (acc0[reg] + acc1[reg] * (1.f / 4096.f)) * iv;
      if (v > rowmin[m]) {
        int k = atomicAdd(&qn[m], 1);
        qv[m * 128 + k] = v;
        qi[m * 128 + k] = gn;
      }
    }
    __syncthreads();
    if (t < 32) {
      int n = qn[t];
      for (int k = 0; k < n; ++k) {
        float v = qv[t * 128 + k];
        int mm = qi[t * 128 + k];
        if (v > av[9]) {
#pragma unroll
          for (int i = 0; i < 10; ++i) {
            if (v > av[i]) {
              float tv = av[i]; av[i] = v; v = tv;
              int ti = ai[i]; ai[i] = mm; mm = ti;
            }
          }
        }
      }
      qn[t] = 0;
      rowmin[t] = av[9];
    }
    __syncthreads();
  }

  if (t < 32) {
    const size_t base = (size_t)(rowbase + t) * 160 + blockIdx.y * 10;
#pragma unroll
    for (int k = 0; k < 10; ++k) {
      topvw[base + k] = av[k];
      topiw[base + k] = ai[k];
    }
  }
}

// ---------------------------------------------------------------------------
// Kernel 3b: merge 16x10 candidates -> exact top-10 -> softmax -> blend (f16).
// ---------------------------------------------------------------------------
__global__ __launch_bounds__(256) void match_merge(
    const float* __restrict__ topvw, const int* __restrict__ topiw,
    const float* __restrict__ memg, _Float16* __restrict__ zmf16) {
  __shared__ float topw[8][10];
  __shared__ int topidx[8][10];
  const int t = threadIdx.x;
  const int rowbase = blockIdx.x * 8;

  if (t < 8) {
    float av[10];
    int ai[10];
#pragma unroll
    for (int i = 0; i < 10; ++i) { av[i] = -FLT_MAX; ai[i] = 0; }
    const size_t base = (size_t)(rowbase + t) * 160;
    for (int c = 0; c < 160; ++c) {
      float v = topvw[base + c];
      int m = topiw[base + c];
      if (v > av[9]) {
#pragma unroll
        for (int i = 0; i < 10; ++i) {
          if (v > av[i]) {
            float tv = av[i]; av[i] = v; v = tv;
            int ti = ai[i]; ai[i] = m; m = ti;
          }
        }
      }
    }
    float e_[10], s = 0.f;
#pragma unroll
    for (int k = 0; k < 10; ++k) { e_[k] = expf(av[k]); s += e_[k]; }
    float inv = 1.f / s;
#pragma unroll
    for (int k = 0; k < 10; ++k) { topw[t][k] = e_[k] * inv; topidx[t][k] = ai[k]; }
  }
  __syncthreads();
  for (int e = t; e < 8 * 128; e += TPB) {
    int r = e >> 7, d = e & 127;
    float o = 0.f;
#pragma unroll
    for (int k = 0; k < 10; ++k)
      o += topw[r][k] * memg[(size_t)topidx[r][k] * 128 + d];
    zmf16[(size_t)(rowbase + r) * 128 + d] = (_Float16)o;
  }
}

// ---------------------------------------------------------------------------
// Kernel 4: decoder FC via f16 MFMA.
// ---------------------------------------------------------------------------
__global__ __launch_bounds__(256) void decfc_kernel(
    const _Float16* __restrict__ zmf16, const float* __restrict__ fcb,
    const float* __restrict__ dfcfrags, _Float16* __restrict__ d0f16) {
  const int t = threadIdx.x;
  const int lane = t & 63;
  const int wv = t >> 6;
  const int r0 = blockIdx.x * 32;
  const int ntbase = blockIdx.y * 49;

  half8 a[8];
  {
    const _Float16* ap =
        zmf16 + (size_t)(r0 + (lane & 31)) * 128 + (lane >> 5) * 8;
#pragma unroll
    for (int ks = 0; ks < 8; ++ks) a[ks] = *(const half8*)(ap + ks * 16);
  }
  const char* fb = (const char*)dfcfrags + lane * 16;

  for (int nt = ntbase + wv; nt < ntbase + 49; nt += 4) {
    half8 bfr[8];
    const char* p = fb + (size_t)nt * 8192;
#pragma unroll
    for (int ks = 0; ks < 8; ++ks) bfr[ks] = *(const half8*)(p + ks * 1024);
    floatx16 acc = {};
#pragma unroll
    for (int ks = 0; ks < 8; ++ks)
      acc = __builtin_amdgcn_mfma_f32_32x32x16_f16(a[ks], bfr[ks], acc, 0, 0, 0);
    const int col = nt * 32 + (lane & 31);
    const int px = col >> 6, c = col & 63;
    const float bias = fcb[c * 49 + px];
#pragma unroll
    for (int reg = 0; reg < 16; ++reg) {
      int row = (reg & 3) + 8 * (reg >> 2) + 4 * (lane >> 5);
      d0f16[((size_t)(r0 + row) * 49 + px) * 64 + c] = (_Float16)(acc[reg] + bias);
    }
  }
}

// ---------------------------------------------------------------------------
// Kernel 5: decoder v4 — deconv1 + conv2 via f16 MFMA.
// ---------------------------------------------------------------------------
__global__ __launch_bounds__(256) void decoder_kernel(
    const _Float16* __restrict__ d0f16, const float* __restrict__ b1,
    const float* __restrict__ w2, const float* __restrict__ b2,
    const float* __restrict__ w3, const float* __restrict__ b3,
    const float* __restrict__ w4, const float* __restrict__ b4,
    const float* __restrict__ dec1frags, float* __restrict__ out) {
  __shared__ __align__(16) char dsm[41408];
  char* d0f = dsm;
  float* d2 = (float*)dsm;
  char* d1f = dsm + 12608;
  char* w2s = dsm + 28992;
  float* d3 = (float*)(dsm + 12608);

  const int b = blockIdx.x;
  const int t = threadIdx.x;
  const int lane = t & 63;
  const int wv = t >> 6;

  for (int e = t; e < 648; e += TPB) {
    int g = e / 81, pix = e - g * 81;
    int ih = pix / 9 - 1, iw = pix % 9 - 1;
    half8 hv = {};
    if (ih >= 0 && ih < 7 && iw >= 0 && iw < 7)
      hv = *(const half8*)(d0f16 + ((size_t)b * 49 + ih * 7 + iw) * 64 + g * 8);
    *(half8*)(d0f + e * 16) = hv;
  }
  for (int e = t; e < 576; e += TPB) {
    int tau = e / 64, l = e - tau * 64;
    int n = l & 15, kq = l >> 4;
    half8 v;
#pragma unroll
    for (int u = 0; u < 8; ++u)
      v[u] = (_Float16)w2[(n * 32 + kq * 8 + u) * 9 + tau];
    *(half8*)(w2s + e * 16) = v;
  }
  for (int e = t; e < 1024; e += TPB)
    *(float4*)(d1f + e * 16) = make_float4(0.f, 0.f, 0.f, 0.f);
  __syncthreads();

  {
    const int pa = wv >> 1, pb = wv & 1;
    const int kg = lane >> 5, o = lane & 31;
    const char* bg = (const char*)dec1frags + wv * 16384 + lane * 16;
    int pxa[2][4];
#pragma unroll
    for (int im = 0; im < 2; ++im) {
      int px = im * 32 + o;
      px = px < 49 ? px : 48;
      int i = px / 7, j2 = px - i * 7;
#pragma unroll
      for (int st = 0; st < 4; ++st) {
        int s = st >> 1, tt = st & 1;
        pxa[im][st] = ((i + pa + s) * 9 + (j2 + pb + tt)) * 16;
      }
    }
    floatx16 acc0 = {}, acc1 = {};
    half8 nb = *(const half8*)(bg);
#pragma unroll
    for (int ks = 0; ks < 16; ++ks) {
      half8 bf = nb;
      if (ks < 15) nb = *(const half8*)(bg + (ks + 1) * 1024);
      const int gbase = (((ks & 3) * 2 + kg) * 81) * 16;
      half8 a0 = *(const half8*)(d0f + gbase + pxa[0][ks >> 2]);
      half8 a1 = *(const half8*)(d0f + gbase + pxa[1][ks >> 2]);
      acc0 = __builtin_amdgcn_mfma_f32_32x32x16_f16(a0, bf, acc0, 0, 0, 0);
      acc1 = __builtin_amdgcn_mfma_f32_32x32x16_f16(a1, bf, acc1, 0, 0, 0);
    }
    const float bias = b1[o];
    char* dst = d1f + (o >> 3) * 4096 + (o & 7) * 2;
#pragma unroll
    for (int im = 0; im < 2; ++im) {
      const floatx16& ac = im ? acc1 : acc0;
#pragma unroll
      for (int reg = 0; reg < 16; ++reg) {
        int row = (reg & 3) + 8 * (reg >> 2) + 4 * kg;
        int px = im * 32 + row;
        if (px < 49) {
          int i = px / 7, j2 = px - i * 7;
          int p = 2 * i + pa, q = 2 * j2 + pb;
          *(_Float16*)(dst + ((p + 1) * 16 + (q + 1)) * 16) =
              (_Float16)fmaxf(ac[reg] + bias, 0.f);
        }
      }
    }
  }
  __syncthreads();

  {
    const int m = lane & 15, kq = lane >> 4;
    half8 bq[9];
#pragma unroll
    for (int tau = 0; tau < 9; ++tau)
      bq[tau] = *(const half8*)(w2s + (tau * 64 + lane) * 16);
    for (int mt = wv; mt < 13; mt += 4) {
      int px = mt * 16 + m;
      px = px < 196 ? px : 195;
      const int p = px / 14, q = px - (px / 14) * 14;
      floatx4 acc = {};
#pragma unroll
      for (int tau = 0; tau < 9; ++tau) {
        const int dp = tau / 3, dq = tau - dp * 3;
        half8 av =
            *(const half8*)(d1f + (kq * 256 + (p + dp) * 16 + (q + dq)) * 16);
        acc = __builtin_amdgcn_mfma_f32_16x16x32_f16(av, bq[tau], acc, 0, 0, 0);
      }
      const int o = lane & 15;
      const float bias = b2[o];
#pragma unroll
      for (int reg = 0; reg < 4; ++reg) {
        int row = (lane >> 4) * 4 + reg;
        int opx = mt * 16 + row;
        if (opx < 196) d2[o * 197 + opx] = fmaxf(acc[reg] + bias, 0.f);
      }
    }
  }
  __syncthreads();
  for (int e = t; e < 7200; e += TPB) d3[e] = 0.f;
  __syncthreads();

  {
    const int ph = __builtin_amdgcn_readfirstlane(t >> 6);
    const int pa = ph >> 1, pb = ph & 1;
    const int tb = pa * 4 + pb;
    const float* wA = w3 + (size_t)tb * 128;
    const float* wB = w3 + (size_t)(tb + 2) * 128;
    const float* wC = w3 + (size_t)(tb + 8) * 128;
    const float* wD = w3 + (size_t)(tb + 10) * 128;
#pragma unroll 1
    for (int k = 0; k < 4; ++k) {
      const int px = lane + 64 * k;
      const int cpx = px < 196 ? px : 195;
      const int i = cpx / 14, j = cpx % 14;
      int ih[2], iw[2];
      float mh[2], mw[2];
#pragma unroll
      for (int s = 0; s < 2; ++s) {
        int v = i + pa + s - 1;
        mh[s] = (v >= 0 && v <= 13) ? 1.f : 0.f;
        ih[s] = v < 0 ? 0 : (v > 13 ? 13 : v);
        int u = j + pb + s - 1;
        mw[s] = (u >= 0 && u <= 13) ? 1.f : 0.f;
        iw[s] = u < 0 ? 0 : (u > 13 ? 13 : u);
      }
      const float m00 = mh[0] * mw[0], m01 = mh[0] * mw[1];
      const float m10 = mh[1] * mw[0], m11 = mh[1] * mw[1];
      float acc[8];
#pragma unroll
      for (int oo = 0; oo < 8; ++oo) acc[oo] = b3[oo];
#pragma unroll 2
      for (int c = 0; c < 16; ++c) {
        const float a00 = d2[c * 197 + ih[0] * 14 + iw[0]] * m00;
        const float a01 = d2[c * 197 + ih[0] * 14 + iw[1]] * m01;
        const float a10 = d2[c * 197 + ih[1] * 14 + iw[0]] * m10;
        const float a11 = d2[c * 197 + ih[1] * 14 + iw[1]] * m11;
        const int wb = c * 8;
#pragma unroll
        for (int oo = 0; oo < 8; ++oo)
          acc[oo] += a00 * wA[wb + oo] + a01 * wB[wb + oo] +
                     a10 * wC[wb + oo] + a11 * wD[wb + oo];
      }
      if (px < 196) {
        const int p = 2 * i + pa, q = 2 * j + pb;
        const int widx = (p + 1) * 30 + (q + 1);
#pragma unroll
        for (int oo = 0; oo < 8; ++oo)
          d3[oo * 900 + widx] = fmaxf(acc[oo], 0.f);
      }
    }
  }
  __syncthreads();

  for (int e = t; e < 784; e += TPB) {
    int p = e / 28, q = e - p * 28;
    float a = b4[0];
#pragma unroll
    for (int c = 0; c < 8; ++c) {
      const float* bp = &d3[c * 900 + p * 30 + q];
#pragma unroll
      for (int di = 0; di < 3; ++di)
#pragma unroll
        for (int dj = 0; dj < 3; ++dj)
          a += bp[di * 30 + dj] * w4[c * 9 + di * 3 + dj];
    }
    out[(size_t)b * 784 + e] = a;
  }
}

// ---------------------------------------------------------------------------
extern "C" void kernel_launch(void* const* d_in, const int* in_sizes, int n_in,
                              void* d_out, int out_size, void* d_ws,
                              size_t ws_size, hipStream_t stream) {
  const float* x      = (const float*)d_in[0];
  const float* ce_w1  = (const float*)d_in[1];
  const float* ce_b1  = (const float*)d_in[2];
  const float* ce_w2  = (const float*)d_in[3];
  const float* ce_b2  = (const float*)d_in[4];
  const float* ce_fcw = (const float*)d_in[5];
  const float* ce_fcb = (const float*)d_in[6];
  const float* ge_w1  = (const float*)d_in[7];
  const float* ge_b1  = (const float*)d_in[8];
  const float* ge_w2  = (const float*)d_in[9];
  const float* ge_b2  = (const float*)d_in[10];
  const float* ge_fcw = (const float*)d_in[11];
  const float* ge_fcb = (const float*)d_in[12];
  const float* memg   = (const float*)d_in[13];
  const float* dfcw   = (const float*)d_in[14];
  const float* dfcb   = (const float*)d_in[15];
  const float* d_w1   = (const float*)d_in[16];
  const float* d_b1   = (const float*)d_in[17];
  const float* d_w2   = (const float*)d_in[18];
  const float* d_b2   = (const float*)d_in[19];
  const float* d_w3   = (const float*)d_in[20];
  const float* d_b3   = (const float*)d_in[21];
  const float* d_w4   = (const float*)d_in[22];
  const float* d_b4   = (const float*)d_in[23];
  float* outp = (float*)d_out;

  float*     ws        = (float*)d_ws;
  float*     z         = ws;
  _Float16*  zmf16     = (_Float16*)(ws + 262144);
  float*     invn      = ws + 262144 + 131072;
  float*     frags     = invn + 8192;
  float*     dec1frags = frags + 36864;
  float*     dfcfrags  = dec1frags + 16384;
  float*     memfrags  = dfcfrags + 200704;
  float*     tailbase  = memfrags + 1048576;
  float*     topvw     = tailbase;
  int*       topiw     = (int*)(tailbase + 327680);
  _Float16*  d0f16     = (_Float16*)tailbase;

  prep_bfrags<<<144, 64, 0, stream>>>(ce_w2, ge_w2, frags);
  prep_dec1<<<64, 64, 0, stream>>>(d_w1, dec1frags);
  prep_dfc<<<784, 64, 0, stream>>>(dfcw, dfcfrags);
  prep_mem<<<4096, 64, 0, stream>>>(memg, memfrags);
  norm_kernel<<<2048, TPB, 0, stream>>>(memg, invn);
  encoders_fused<<<4096, TPB, 0, stream>>>(x, ce_w1, ce_b1, ce_b2, ce_fcw,
                                           ce_fcb, ge_w1, ge_b1, ge_b2, ge_fcw,
                                           ge_fcb, frags, z);
  match_mfma<<<dim3(64, 16), TPB, 0, stream>>>(z, memfrags, invn, topvw, topiw);
  match_merge<<<256, TPB, 0, stream>>>(topvw, topiw, memg, zmf16);
  decfc_kernel<<<dim3(64, 2), TPB, 0, stream>>>(zmf16, dfcb, dfcfrags, d0f16);
  decoder_kernel<<<2048, TPB, 0, stream>>>(d0f16, d_b1, d_w2, d_b2, d_w3, d_b3,
                                           d_w4, d_b4, dec1frags, outp);
}

// Round 7
// 666.588 us; speedup vs baseline: 3.3138x; 2.8323x over previous
//
#include <hip/hip_runtime.h>
#include <cfloat>
#include <cmath>

#define TPB 256

typedef _Float16 half8 __attribute__((ext_vector_type(8)));
typedef float floatx16 __attribute__((ext_vector_type(16)));
typedef float floatx4 __attribute__((ext_vector_type(4)));

__device__ __forceinline__ float wave_reduce_sum(float v) {
#pragma unroll
  for (int off = 32; off > 0; off >>= 1) v += __shfl_xor(v, off, 64);
  return v;
}

// ---------------------------------------------------------------------------
// Kernel 0a: encoder conv2 B-fragments (2-part f16 split).
// ---------------------------------------------------------------------------
__global__ __launch_bounds__(64) void prep_bfrags(
    const float* __restrict__ ce_w2, const float* __restrict__ ge_w2,
    float* __restrict__ frags) {
  const int blk = blockIdx.x;  // 144 = 2 enc x 72 frags
  const int enc = blk / 72;
  const int frag = blk % 72;
  const int ks = frag >> 2, part = (frag >> 1) & 1, nt = frag & 1;
  const int tap = ks >> 1, half = ks & 1;
  const int lane = threadIdx.x;
  const float* w2 = enc ? ge_w2 : ce_w2;
  const int n = nt * 32 + (lane & 31);
  const int cb = half * 16 + (lane >> 5) * 8;
  half8 out;
#pragma unroll
  for (int j = 0; j < 8; ++j) {
    float v = w2[(n * 32 + cb + j) * 9 + tap];
    _Float16 h = (_Float16)v;
    out[j] = (part == 0) ? h : (_Float16)((v - (float)h) * 4096.f);
  }
  *(half8*)((char*)frags + ((size_t)blk * 64 + lane) * 16) = out;
}

// ---------------------------------------------------------------------------
// Kernel 0b: decoder deconv1 B-fragments (single f16).
// ---------------------------------------------------------------------------
__global__ __launch_bounds__(64) void prep_dec1(
    const float* __restrict__ w1, float* __restrict__ frags) {
  const int blk = blockIdx.x;
  const int phase = blk >> 4, ks = blk & 15;
  const int pa = phase >> 1, pb = phase & 1;
  const int st = ks >> 2, kk = ks & 3;
  const int s = st >> 1, tt = st & 1;
  const int lane = threadIdx.x;
  const int kg = lane >> 5, n = lane & 31;
  const int tap = (pa + 2 * s) * 4 + (pb + 2 * tt);
  half8 o;
#pragma unroll
  for (int j = 0; j < 8; ++j) {
    int c = kk * 16 + kg * 8 + j;
    o[j] = (_Float16)w1[tap * 2048 + c * 32 + n];
  }
  *(half8*)((char*)frags + ((size_t)blk * 64 + lane) * 16) = o;
}

// ---------------------------------------------------------------------------
// Kernel 0c: decfc B-fragments (f16).
// ---------------------------------------------------------------------------
__global__ __launch_bounds__(64) void prep_dfc(
    const float* __restrict__ dfcw, float* __restrict__ frags) {
  const int blk = blockIdx.x;  // 784 = 98 nt x 8 ks
  const int nt = blk >> 3, ks = blk & 7;
  const int lane = threadIdx.x;
  const int n = lane & 31, kg = lane >> 5;
  const int j = nt * 32 + n;
  const int px = j >> 6, c = j & 63;
  half8 o;
#pragma unroll
  for (int u = 0; u < 8; ++u)
    o[u] = (_Float16)dfcw[(size_t)(c * 49 + px) * 128 + ks * 16 + kg * 8 + u];
  *(half8*)((char*)frags + ((size_t)blk * 64 + lane) * 16) = o;
}

// ---------------------------------------------------------------------------
// Kernel 0d: mem B-fragments for match (2-part f16 split).
// ---------------------------------------------------------------------------
__global__ __launch_bounds__(64) void prep_mem(
    const float* __restrict__ memg, float* __restrict__ frags) {
  const int blk = blockIdx.x;  // 4096 = 256 tiles x 16 slots
  const int slot = blk & 15;
  const int p = slot >> 3, ks = slot & 7;
  const int T = blk >> 4;
  const int lane = threadIdx.x;
  const int n = lane & 31, kg = lane >> 5;
  const float* src = memg + (size_t)(T * 32 + n) * 128 + ks * 16 + kg * 8;
  half8 o;
#pragma unroll
  for (int j = 0; j < 8; ++j) {
    float v = src[j];
    _Float16 h = (_Float16)v;
    o[j] = p ? (_Float16)((v - (float)h) * 4096.f) : h;
  }
  *(half8*)((char*)frags + ((size_t)blk * 64 + lane) * 16) = o;
}

// ---------------------------------------------------------------------------
// Kernel 1: memory row inverse norms
// ---------------------------------------------------------------------------
__global__ __launch_bounds__(256) void norm_kernel(
    const float* __restrict__ memg, float* __restrict__ invn) {
  const int wv = threadIdx.x >> 6, lane = threadIdx.x & 63;
  const int row = blockIdx.x * 4 + wv;
  const float* r = memg + (size_t)row * 128;
  float a = r[lane], b = r[lane + 64];
  float s = wave_reduce_sum(a * a + b * b);
  if (lane == 0) invn[row] = 1.f / fmaxf(sqrtf(s), 1e-12f);
}

// ---------------------------------------------------------------------------
// Kernel 2: MFMA encoder (v4 — proven 308us, no spill).
// Bands of 7 rows (uniform), 4 blocks/CU, MFMA unit = (M-tile, both nt).
// NOTE: unified VGPR+AGPR file: 64 arch + 64 acc = exactly the 128/wave cap
// at (256,4). Any added register pressure (prefetch rings etc.) spills
// catastrophically (v6: 2.6GB, v7: 2.2GB scratch traffic). Do not pipeline
// this loop at source level.
// ---------------------------------------------------------------------------
template <int S, bool CENTER>
__device__ __forceinline__ void encoder_body(
    char* smem, const float* __restrict__ x, const float* __restrict__ w1,
    const float* __restrict__ b1, const float* __restrict__ b2,
    const float* __restrict__ fcw, const float* __restrict__ fcb,
    const float* __restrict__ bfrag, float* __restrict__ zout, int zoff,
    int b) {
  constexpr int SP = S + 2;
  constexpr int NBANDS = S / 7;      // 4 (global) or 2 (center)
  constexpr int NPIX = 9 * SP;       // 7 output rows + 2 halo
  constexpr int GSTB = NPIX * 16;
  constexpr int PSTB = 4 * GSTB;
  constexpr int LIMIT = 7 * S;       // pixels per band
  constexpr int MTB = (LIMIT + 31) / 32;

  char* h1s = smem;
  float* xs = (float*)(smem + 2 * PSTB);
  float* w1s = xs + SP * SP;
  float* featp = w1s + 288;  // [4][64]

  const int t = threadIdx.x;
  const int lane = t & 63;
  const int wv = t >> 6;

  for (int e = t; e < SP * SP; e += TPB) xs[e] = 0.f;
  for (int e = t; e < 288; e += TPB) w1s[e] = w1[e];
  __syncthreads();
  const float* xb = x + (size_t)b * 784 + (CENTER ? (7 * 28 + 7) : 0);
  for (int e = t; e < S * S; e += TPB) {
    int i = e / S, j = e - i * S;
    xs[(i + 1) * SP + (j + 1)] = xb[i * 28 + j];
  }

  float sp0 = 0.f, sp1 = 0.f;
  const float bias0 = b2[lane & 31];
  const float bias1 = b2[32 + (lane & 31)];
  const int gOff = (lane >> 5) * GSTB;
  const char* bgbase = (const char*)bfrag + lane * 16;

#pragma unroll 1
  for (int band = 0; band < NBANDS; ++band) {
    const int b0 = band * 7;

    __syncthreads();
    for (int e = t; e < 4 * NPIX; e += TPB) {
      int g = e / NPIX;
      int pix = e - g * NPIX;
      int lr = pix / SP;
      int cw = pix - lr * SP;
      int gr = b0 - 1 + lr;
      int ebase = g * GSTB + pix * 16;
      half8 hi8 = {}, lo8 = {};
      if (gr >= 0 && gr < S && cw >= 1 && cw <= S) {
        float xv[9];
#pragma unroll
        for (int di = 0; di < 3; ++di)
#pragma unroll
          for (int dj = 0; dj < 3; ++dj)
            xv[di * 3 + dj] = xs[(gr + di) * SP + (cw - 1 + dj)];
#pragma unroll
        for (int u = 0; u < 8; ++u) {
          int ch = g * 8 + u;
          float a = b1[ch];
#pragma unroll
          for (int v = 0; v < 9; ++v) a += xv[v] * w1s[ch * 9 + v];
          a = fmaxf(a, 0.f);
          _Float16 h = (_Float16)a;
          hi8[u] = h;
          lo8[u] = (_Float16)((a - (float)h) * 4096.f);
        }
      }
      *(half8*)(h1s + ebase) = hi8;
      *(half8*)(h1s + PSTB + ebase) = lo8;
    }
    __syncthreads();
    // MFMA: unit = (single M-tile, both nt); A-frags shared across nt
#pragma unroll 1
    for (int mt = wv; mt < MTB; mt += 4) {
      floatx16 aH0 = {}, aL0 = {}, aH1 = {}, aL1 = {};
      int px = mt * 32 + (lane & 31);
      px = px < LIMIT ? px : LIMIT - 1;
      const int r = px / S, cc = px - r * S;
      const int pixB = (r * SP + cc) * 16;
#pragma unroll 3
      for (int tap = 0; tap < 9; ++tap) {
        const int di = tap / 3, dj = tap - di * 3;
        const int offT = (di * SP + dj) * 16;
#pragma unroll
        for (int half = 0; half < 2; ++half) {
          const int ks = tap * 2 + half;
          const char* bp = bgbase + ks * 4096;
          const int offA = pixB + offT + gOff + half * (2 * GSTB);
          half8 ah = *(const half8*)(h1s + offA);
          half8 al = *(const half8*)(h1s + PSTB + offA);
          {  // nt = 0
            half8 bh = *(const half8*)(bp);
            half8 bl = *(const half8*)(bp + 2048);
            aH0 = __builtin_amdgcn_mfma_f32_32x32x16_f16(ah, bh, aH0, 0, 0, 0);
            aL0 = __builtin_amdgcn_mfma_f32_32x32x16_f16(ah, bl, aL0, 0, 0, 0);
            aL0 = __builtin_amdgcn_mfma_f32_32x32x16_f16(al, bh, aL0, 0, 0, 0);
          }
          {  // nt = 1
            half8 bh = *(const half8*)(bp + 1024);
            half8 bl = *(const half8*)(bp + 3072);
            aH1 = __builtin_amdgcn_mfma_f32_32x32x16_f16(ah, bh, aH1, 0, 0, 0);
            aL1 = __builtin_amdgcn_mfma_f32_32x32x16_f16(ah, bl, aL1, 0, 0, 0);
            aL1 = __builtin_amdgcn_mfma_f32_32x32x16_f16(al, bh, aL1, 0, 0, 0);
          }
        }
      }
#pragma unroll
      for (int reg = 0; reg < 16; ++reg) {
        int row = (reg & 3) + 8 * (reg >> 2) + 4 * (lane >> 5);
        int p = mt * 32 + row;
        if (p < LIMIT) {
          sp0 += fmaxf(aH0[reg] + aL0[reg] * (1.f / 4096.f) + bias0, 0.f);
          sp1 += fmaxf(aH1[reg] + aL1[reg] * (1.f / 4096.f) + bias1, 0.f);
        }
      }
    }
  }
  sp0 += __shfl_xor(sp0, 32);
  sp1 += __shfl_xor(sp1, 32);
  if (lane < 32) {
    featp[wv * 64 + lane] = sp0;
    featp[wv * 64 + 32 + lane] = sp1;
  }
  __syncthreads();
  if (t < 64)
    featp[t] = (featp[t] + featp[64 + t] + featp[128 + t] + featp[192 + t]) *
               (1.f / (S * S));
  __syncthreads();
  if (t < 64) {
    float s = 0.f;
#pragma unroll
    for (int i = 0; i < 64; ++i) s += featp[i] * fcw[t * 64 + i];
    zout[(size_t)b * 128 + zoff + t] = s + fcb[t];
  }
}

__global__ __launch_bounds__(256, 4) void encoders_fused(
    const float* __restrict__ x, const float* __restrict__ ce_w1,
    const float* __restrict__ ce_b1, const float* __restrict__ ce_b2,
    const float* __restrict__ ce_fcw, const float* __restrict__ ce_fcb,
    const float* __restrict__ ge_w1, const float* __restrict__ ge_b1,
    const float* __restrict__ ge_b2, const float* __restrict__ ge_fcw,
    const float* __restrict__ ge_fcb, const float* __restrict__ frags,
    float* __restrict__ z) {
  // S=28: 2*PSTB(34560) + xs(3600) + w1s(1152) + featp(1024) = 40336 -> 4/CU
  __shared__ __align__(16) char smem[40336];
  if (blockIdx.x < 2048)
    encoder_body<28, false>(smem, x, ge_w1, ge_b1, ge_b2, ge_fcw, ge_fcb,
                            frags + 18432, z, 64, blockIdx.x);
  else
    encoder_body<14, true>(smem, x, ce_w1, ce_b1, ce_b2, ce_fcw, ce_fcb, frags,
                           z, 0, blockIdx.x - 2048);
}

// ---------------------------------------------------------------------------
// Kernel 2b (new): z normalize + A-fragment build, ONCE per 32-row z-block.
// Previously repeated inside all 16 y-slices of match_mfma (16x redundant).
// Writes 16KB/block of frag data (hi 8KB | lo 8KB) to workspace.
// ---------------------------------------------------------------------------
__global__ __launch_bounds__(256) void zprep_kernel(
    const float* __restrict__ z, float* __restrict__ zfragg) {
  __shared__ __align__(16) float zs[4096];
  __shared__ __align__(16) char zfrag[16384];
  const int t = threadIdx.x;
  const int lane = t & 63;
  const int wv = t >> 6;
  const int rowbase = blockIdx.x * 32;

  for (int e = t; e < 4096; e += TPB) zs[e] = z[(size_t)rowbase * 128 + e];
  __syncthreads();
#pragma unroll
  for (int h = 0; h < 8; ++h) {
    int r = wv * 8 + h;
    float a = zs[r * 128 + lane], b = zs[r * 128 + 64 + lane];
    float s = wave_reduce_sum(a * a + b * b);
    float inv = 1.f / fmaxf(sqrtf(s), 1e-12f);
    zs[r * 128 + lane] = a * inv;
    zs[r * 128 + 64 + lane] = b * inv;
  }
  __syncthreads();
  for (int e = t; e < 4096; e += TPB) {
    int m = e >> 7, c = e & 127;
    float v = zs[m * 128 + c];
    _Float16 h = (_Float16)v;
    _Float16 l = (_Float16)((v - (float)h) * 4096.f);
    int ks = c >> 4, kg = (c >> 3) & 1, j = c & 7;
    int off = (ks * 64 + kg * 32 + m) * 16 + j * 2;
    *(_Float16*)(zfrag + off) = h;
    *(_Float16*)(zfrag + 8192 + off) = l;
  }
  __syncthreads();
  const float4* src = (const float4*)zfrag;
  float4* dst = (float4*)(zfragg + (size_t)blockIdx.x * 4096);
  for (int e = t; e < 1024; e += TPB) dst[e] = src[e];
}

// ---------------------------------------------------------------------------
// Kernel 3a: match via split-f16 MFMA. v8: A-fragments loaded directly from
// precomputed zfragg (L2-hot: 16 consumers per 16KB block). LDS 49->33KB
// (4 blocks/CU), prologue (z load+norm+frag build+2 barriers) removed.
// ---------------------------------------------------------------------------
__global__ __launch_bounds__(256) void match_mfma(
    const float* __restrict__ zfragg, const float* __restrict__ memfrags,
    const float* __restrict__ invn, float* __restrict__ topvw,
    int* __restrict__ topiw) {
  __shared__ __align__(16) char smem[33024];
  float* qv = (float*)smem;            // [32][128]
  int* qi = (int*)(smem + 16384);      // [32][128]
  float* rowmin = (float*)(smem + 32768);
  int* qn = (int*)(smem + 32768 + 128);

  const int t = threadIdx.x;
  const int lane = t & 63;
  const int wv = t >> 6;
  const int rowbase = blockIdx.x * 32;
  const int Tbase = blockIdx.y * 16;

  if (t < 32) { rowmin[t] = -FLT_MAX; qn[t] = 0; }

  // load A-fragments from global (constant across all 16 n-tiles)
  half8 ah[8], al[8];
  {
    const char* zf = (const char*)zfragg + (size_t)blockIdx.x * 16384 +
                     ((lane >> 5) * 32 + (lane & 31)) * 16;
#pragma unroll
    for (int ks = 0; ks < 8; ++ks) {
      ah[ks] = *(const half8*)(zf + ks * 1024);
      al[ks] = *(const half8*)(zf + 8192 + ks * 1024);
    }
  }
  __syncthreads();

  float av[10];
  int ai[10];
#pragma unroll
  for (int i = 0; i < 10; ++i) { av[i] = -FLT_MAX; ai[i] = 0; }

#pragma unroll 1
  for (int round = 0; round < 4; ++round) {
    const int T = Tbase + round * 4 + wv;
    const char* bf = (const char*)memfrags + (size_t)T * 16384 + lane * 16;
    floatx16 acc0 = {}, acc1 = {};
#pragma unroll
    for (int ks = 0; ks < 8; ++ks) {
      half8 bh = *(const half8*)(bf + ks * 1024);
      half8 bl = *(const half8*)(bf + 8192 + ks * 1024);
      acc0 = __builtin_amdgcn_mfma_f32_32x32x16_f16(ah[ks], bh, acc0, 0, 0, 0);
      acc1 = __builtin_amdgcn_mfma_f32_32x32x16_f16(ah[ks], bl, acc1, 0, 0, 0);
      acc1 = __builtin_amdgcn_mfma_f32_32x32x16_f16(al[ks], bh, acc1, 0, 0, 0);
    }
    const int gn = T * 32 + (lane & 31);
    const float iv = invn[gn];
#pragma unroll
    for (int reg = 0; reg < 16; ++reg) {
      int m = (reg & 3) + 8 * (reg >> 2) + 4 * (lane >> 5);
      float v = (acc0[reg] + acc1[reg] * (1.f / 4096.f)) * iv;
      if (v > rowmin[m]) {
        int k = atomicAdd(&qn[m], 1);
        qv[m * 128 + k] = v;
        qi[m * 128 + k] = gn;
      }
    }
    __syncthreads();
    if (t < 32) {
      int n = qn[t];
      for (int k = 0; k < n; ++k) {
        float v = qv[t * 128 + k];
        int mm = qi[t * 128 + k];
        if (v > av[9]) {
#pragma unroll
          for (int i = 0; i < 10; ++i) {
            if (v > av[i]) {
              float tv = av[i]; av[i] = v; v = tv;
              int ti = ai[i]; ai[i] = mm; mm = ti;
            }
          }
        }
      }
      qn[t] = 0;
      rowmin[t] = av[9];
    }
    __syncthreads();
  }

  if (t < 32) {
    const size_t base = (size_t)(rowbase + t) * 160 + blockIdx.y * 10;
#pragma unroll
    for (int k = 0; k < 10; ++k) {
      topvw[base + k] = av[k];
      topiw[base + k] = ai[k];
    }
  }
}

// ---------------------------------------------------------------------------
// Kernel 3b: merge 16x10 candidates -> exact top-10 -> softmax -> blend (f16).
// ---------------------------------------------------------------------------
__global__ __launch_bounds__(256) void match_merge(
    const float* __restrict__ topvw, const int* __restrict__ topiw,
    const float* __restrict__ memg, _Float16* __restrict__ zmf16) {
  __shared__ float topw[8][10];
  __shared__ int topidx[8][10];
  const int t = threadIdx.x;
  const int rowbase = blockIdx.x * 8;

  if (t < 8) {
    float av[10];
    int ai[10];
#pragma unroll
    for (int i = 0; i < 10; ++i) { av[i] = -FLT_MAX; ai[i] = 0; }
    const size_t base = (size_t)(rowbase + t) * 160;
    for (int c = 0; c < 160; ++c) {
      float v = topvw[base + c];
      int m = topiw[base + c];
      if (v > av[9]) {
#pragma unroll
        for (int i = 0; i < 10; ++i) {
          if (v > av[i]) {
            float tv = av[i]; av[i] = v; v = tv;
            int ti = ai[i]; ai[i] = m; m = ti;
          }
        }
      }
    }
    float e_[10], s = 0.f;
#pragma unroll
    for (int k = 0; k < 10; ++k) { e_[k] = expf(av[k]); s += e_[k]; }
    float inv = 1.f / s;
#pragma unroll
    for (int k = 0; k < 10; ++k) { topw[t][k] = e_[k] * inv; topidx[t][k] = ai[k]; }
  }
  __syncthreads();
  for (int e = t; e < 8 * 128; e += TPB) {
    int r = e >> 7, d = e & 127;
    float o = 0.f;
#pragma unroll
    for (int k = 0; k < 10; ++k)
      o += topw[r][k] * memg[(size_t)topidx[r][k] * 128 + d];
    zmf16[(size_t)(rowbase + r) * 128 + d] = (_Float16)o;
  }
}

// ---------------------------------------------------------------------------
// Kernel 4: decoder FC via f16 MFMA.
// ---------------------------------------------------------------------------
__global__ __launch_bounds__(256) void decfc_kernel(
    const _Float16* __restrict__ zmf16, const float* __restrict__ fcb,
    const float* __restrict__ dfcfrags, _Float16* __restrict__ d0f16) {
  const int t = threadIdx.x;
  const int lane = t & 63;
  const int wv = t >> 6;
  const int r0 = blockIdx.x * 32;
  const int ntbase = blockIdx.y * 49;

  half8 a[8];
  {
    const _Float16* ap =
        zmf16 + (size_t)(r0 + (lane & 31)) * 128 + (lane >> 5) * 8;
#pragma unroll
    for (int ks = 0; ks < 8; ++ks) a[ks] = *(const half8*)(ap + ks * 16);
  }
  const char* fb = (const char*)dfcfrags + lane * 16;

  for (int nt = ntbase + wv; nt < ntbase + 49; nt += 4) {
    half8 bfr[8];
    const char* p = fb + (size_t)nt * 8192;
#pragma unroll
    for (int ks = 0; ks < 8; ++ks) bfr[ks] = *(const half8*)(p + ks * 1024);
    floatx16 acc = {};
#pragma unroll
    for (int ks = 0; ks < 8; ++ks)
      acc = __builtin_amdgcn_mfma_f32_32x32x16_f16(a[ks], bfr[ks], acc, 0, 0, 0);
    const int col = nt * 32 + (lane & 31);
    const int px = col >> 6, c = col & 63;
    const float bias = fcb[c * 49 + px];
#pragma unroll
    for (int reg = 0; reg < 16; ++reg) {
      int row = (reg & 3) + 8 * (reg >> 2) + 4 * (lane >> 5);
      d0f16[((size_t)(r0 + row) * 49 + px) * 64 + c] = (_Float16)(acc[reg] + bias);
    }
  }
}

// ---------------------------------------------------------------------------
// Kernel 5: decoder — deconv1 + conv2 via f16 MFMA.
// ---------------------------------------------------------------------------
__global__ __launch_bounds__(256) void decoder_kernel(
    const _Float16* __restrict__ d0f16, const float* __restrict__ b1,
    const float* __restrict__ w2, const float* __restrict__ b2,
    const float* __restrict__ w3, const float* __restrict__ b3,
    const float* __restrict__ w4, const float* __restrict__ b4,
    const float* __restrict__ dec1frags, float* __restrict__ out) {
  __shared__ __align__(16) char dsm[41408];
  char* d0f = dsm;
  float* d2 = (float*)dsm;
  char* d1f = dsm + 12608;
  char* w2s = dsm + 28992;
  float* d3 = (float*)(dsm + 12608);

  const int b = blockIdx.x;
  const int t = threadIdx.x;
  const int lane = t & 63;
  const int wv = t >> 6;

  for (int e = t; e < 648; e += TPB) {
    int g = e / 81, pix = e - g * 81;
    int ih = pix / 9 - 1, iw = pix % 9 - 1;
    half8 hv = {};
    if (ih >= 0 && ih < 7 && iw >= 0 && iw < 7)
      hv = *(const half8*)(d0f16 + ((size_t)b * 49 + ih * 7 + iw) * 64 + g * 8);
    *(half8*)(d0f + e * 16) = hv;
  }
  for (int e = t; e < 576; e += TPB) {
    int tau = e / 64, l = e - tau * 64;
    int n = l & 15, kq = l >> 4;
    half8 v;
#pragma unroll
    for (int u = 0; u < 8; ++u)
      v[u] = (_Float16)w2[(n * 32 + kq * 8 + u) * 9 + tau];
    *(half8*)(w2s + e * 16) = v;
  }
  for (int e = t; e < 1024; e += TPB)
    *(float4*)(d1f + e * 16) = make_float4(0.f, 0.f, 0.f, 0.f);
  __syncthreads();

  {
    const int pa = wv >> 1, pb = wv & 1;
    const int kg = lane >> 5, o = lane & 31;
    const char* bg = (const char*)dec1frags + wv * 16384 + lane * 16;
    int pxa[2][4];
#pragma unroll
    for (int im = 0; im < 2; ++im) {
      int px = im * 32 + o;
      px = px < 49 ? px : 48;
      int i = px / 7, j2 = px - i * 7;
#pragma unroll
      for (int st = 0; st < 4; ++st) {
        int s = st >> 1, tt = st & 1;
        pxa[im][st] = ((i + pa + s) * 9 + (j2 + pb + tt)) * 16;
      }
    }
    floatx16 acc0 = {}, acc1 = {};
    half8 nb = *(const half8*)(bg);
#pragma unroll
    for (int ks = 0; ks < 16; ++ks) {
      half8 bf = nb;
      if (ks < 15) nb = *(const half8*)(bg + (ks + 1) * 1024);
      const int gbase = (((ks & 3) * 2 + kg) * 81) * 16;
      half8 a0 = *(const half8*)(d0f + gbase + pxa[0][ks >> 2]);
      half8 a1 = *(const half8*)(d0f + gbase + pxa[1][ks >> 2]);
      acc0 = __builtin_amdgcn_mfma_f32_32x32x16_f16(a0, bf, acc0, 0, 0, 0);
      acc1 = __builtin_amdgcn_mfma_f32_32x32x16_f16(a1, bf, acc1, 0, 0, 0);
    }
    const float bias = b1[o];
    char* dst = d1f + (o >> 3) * 4096 + (o & 7) * 2;
#pragma unroll
    for (int im = 0; im < 2; ++im) {
      const floatx16& ac = im ? acc1 : acc0;
#pragma unroll
      for (int reg = 0; reg < 16; ++reg) {
        int row = (reg & 3) + 8 * (reg >> 2) + 4 * kg;
        int px = im * 32 + row;
        if (px < 49) {
          int i = px / 7, j2 = px - i * 7;
          int p = 2 * i + pa, q = 2 * j2 + pb;
          *(_Float16*)(dst + ((p + 1) * 16 + (q + 1)) * 16) =
              (_Float16)fmaxf(ac[reg] + bias, 0.f);
        }
      }
    }
  }
  __syncthreads();

  {
    const int m = lane & 15, kq = lane >> 4;
    half8 bq[9];
#pragma unroll
    for (int tau = 0; tau < 9; ++tau)
      bq[tau] = *(const half8*)(w2s + (tau * 64 + lane) * 16);
    for (int mt = wv; mt < 13; mt += 4) {
      int px = mt * 16 + m;
      px = px < 196 ? px : 195;
      const int p = px / 14, q = px - (px / 14) * 14;
      floatx4 acc = {};
#pragma unroll
      for (int tau = 0; tau < 9; ++tau) {
        const int dp = tau / 3, dq = tau - dp * 3;
        half8 av =
            *(const half8*)(d1f + (kq * 256 + (p + dp) * 16 + (q + dq)) * 16);
        acc = __builtin_amdgcn_mfma_f32_16x16x32_f16(av, bq[tau], acc, 0, 0, 0);
      }
      const int o = lane & 15;
      const float bias = b2[o];
#pragma unroll
      for (int reg = 0; reg < 4; ++reg) {
        int row = (lane >> 4) * 4 + reg;
        int opx = mt * 16 + row;
        if (opx < 196) d2[o * 197 + opx] = fmaxf(acc[reg] + bias, 0.f);
      }
    }
  }
  __syncthreads();
  for (int e = t; e < 7200; e += TPB) d3[e] = 0.f;
  __syncthreads();

  {
    const int ph = __builtin_amdgcn_readfirstlane(t >> 6);
    const int pa = ph >> 1, pb = ph & 1;
    const int tb = pa * 4 + pb;
    const float* wA = w3 + (size_t)tb * 128;
    const float* wB = w3 + (size_t)(tb + 2) * 128;
    const float* wC = w3 + (size_t)(tb + 8) * 128;
    const float* wD = w3 + (size_t)(tb + 10) * 128;
#pragma unroll 1
    for (int k = 0; k < 4; ++k) {
      const int px = lane + 64 * k;
      const int cpx = px < 196 ? px : 195;
      const int i = cpx / 14, j = cpx % 14;
      int ih[2], iw[2];
      float mh[2], mw[2];
#pragma unroll
      for (int s = 0; s < 2; ++s) {
        int v = i + pa + s - 1;
        mh[s] = (v >= 0 && v <= 13) ? 1.f : 0.f;
        ih[s] = v < 0 ? 0 : (v > 13 ? 13 : v);
        int u = j + pb + s - 1;
        mw[s] = (u >= 0 && u <= 13) ? 1.f : 0.f;
        iw[s] = u < 0 ? 0 : (u > 13 ? 13 : u);
      }
      const float m00 = mh[0] * mw[0], m01 = mh[0] * mw[1];
      const float m10 = mh[1] * mw[0], m11 = mh[1] * mw[1];
      float acc[8];
#pragma unroll
      for (int oo = 0; oo < 8; ++oo) acc[oo] = b3[oo];
#pragma unroll 2
      for (int c = 0; c < 16; ++c) {
        const float a00 = d2[c * 197 + ih[0] * 14 + iw[0]] * m00;
        const float a01 = d2[c * 197 + ih[0] * 14 + iw[1]] * m01;
        const float a10 = d2[c * 197 + ih[1] * 14 + iw[0]] * m10;
        const float a11 = d2[c * 197 + ih[1] * 14 + iw[1]] * m11;
        const int wb = c * 8;
#pragma unroll
        for (int oo = 0; oo < 8; ++oo)
          acc[oo] += a00 * wA[wb + oo] + a01 * wB[wb + oo] +
                     a10 * wC[wb + oo] + a11 * wD[wb + oo];
      }
      if (px < 196) {
        const int p = 2 * i + pa, q = 2 * j + pb;
        const int widx = (p + 1) * 30 + (q + 1);
#pragma unroll
        for (int oo = 0; oo < 8; ++oo)
          d3[oo * 900 + widx] = fmaxf(acc[oo], 0.f);
      }
    }
  }
  __syncthreads();

  for (int e = t; e < 784; e += TPB) {
    int p = e / 28, q = e - p * 28;
    float a = b4[0];
#pragma unroll
    for (int c = 0; c < 8; ++c) {
      const float* bp = &d3[c * 900 + p * 30 + q];
#pragma unroll
      for (int di = 0; di < 3; ++di)
#pragma unroll
        for (int dj = 0; dj < 3; ++dj)
          a += bp[di * 30 + dj] * w4[c * 9 + di * 3 + dj];
    }
    out[(size_t)b * 784 + e] = a;
  }
}

// ---------------------------------------------------------------------------
extern "C" void kernel_launch(void* const* d_in, const int* in_sizes, int n_in,
                              void* d_out, int out_size, void* d_ws,
                              size_t ws_size, hipStream_t stream) {
  const float* x      = (const float*)d_in[0];
  const float* ce_w1  = (const float*)d_in[1];
  const float* ce_b1  = (const float*)d_in[2];
  const float* ce_w2  = (const float*)d_in[3];
  const float* ce_b2  = (const float*)d_in[4];
  const float* ce_fcw = (const float*)d_in[5];
  const float* ce_fcb = (const float*)d_in[6];
  const float* ge_w1  = (const float*)d_in[7];
  const float* ge_b1  = (const float*)d_in[8];
  const float* ge_w2  = (const float*)d_in[9];
  const float* ge_b2  = (const float*)d_in[10];
  const float* ge_fcw = (const float*)d_in[11];
  const float* ge_fcb = (const float*)d_in[12];
  const float* memg   = (const float*)d_in[13];
  const float* dfcw   = (const float*)d_in[14];
  const float* dfcb   = (const float*)d_in[15];
  const float* d_w1   = (const float*)d_in[16];
  const float* d_b1   = (const float*)d_in[17];
  const float* d_w2   = (const float*)d_in[18];
  const float* d_b2   = (const float*)d_in[19];
  const float* d_w3   = (const float*)d_in[20];
  const float* d_b3   = (const float*)d_in[21];
  const float* d_w4   = (const float*)d_in[22];
  const float* d_b4   = (const float*)d_in[23];
  float* outp = (float*)d_out;

  // ws layout (float offsets): z[262144] | zmf16[131072] | invn[8192] |
  // enc frags[36864] | dec1frags[16384] | dfcfrags[200704] |
  // memfrags[1048576] | tail: topv[327680]+topi[327680]+zfragg[262144]
  // (then d0f16 reuses tail after match completes — sequential).
  float*     ws        = (float*)d_ws;
  float*     z         = ws;
  _Float16*  zmf16     = (_Float16*)(ws + 262144);
  float*     invn      = ws + 262144 + 131072;
  float*     frags     = invn + 8192;
  float*     dec1frags = frags + 36864;
  float*     dfcfrags  = dec1frags + 16384;
  float*     memfrags  = dfcfrags + 200704;
  float*     tailbase  = memfrags + 1048576;
  float*     topvw     = tailbase;
  int*       topiw     = (int*)(tailbase + 327680);
  float*     zfragg    = tailbase + 655360;
  _Float16*  d0f16     = (_Float16*)tailbase;

  prep_bfrags<<<144, 64, 0, stream>>>(ce_w2, ge_w2, frags);
  prep_dec1<<<64, 64, 0, stream>>>(d_w1, dec1frags);
  prep_dfc<<<784, 64, 0, stream>>>(dfcw, dfcfrags);
  prep_mem<<<4096, 64, 0, stream>>>(memg, memfrags);
  norm_kernel<<<2048, TPB, 0, stream>>>(memg, invn);
  encoders_fused<<<4096, TPB, 0, stream>>>(x, ce_w1, ce_b1, ce_b2, ce_fcw,
                                           ce_fcb, ge_w1, ge_b1, ge_b2, ge_fcw,
                                           ge_fcb, frags, z);
  zprep_kernel<<<64, TPB, 0, stream>>>(z, zfragg);
  match_mfma<<<dim3(64, 16), TPB, 0, stream>>>(zfragg, memfrags, invn, topvw,
                                               topiw);
  match_merge<<<256, TPB, 0, stream>>>(topvw, topiw, memg, zmf16);
  decfc_kernel<<<dim3(64, 2), TPB, 0, stream>>>(zmf16, dfcb, dfcfrags, d0f16);
  decoder_kernel<<<2048, TPB, 0, stream>>>(d0f16, d_b1, d_w2, d_b2, d_w3, d_b3,
                                           d_w4, d_b4, dec1frags, outp);
}

// Round 8
// 637.761 us; speedup vs baseline: 3.4636x; 1.0452x over previous
//
#include <hip/hip_runtime.h>
#include <cfloat>
#include <cmath>

#define TPB 256

typedef _Float16 half8 __attribute__((ext_vector_type(8)));
typedef float floatx16 __attribute__((ext_vector_type(16)));
typedef float floatx4 __attribute__((ext_vector_type(4)));

__device__ __forceinline__ float wave_reduce_sum(float v) {
#pragma unroll
  for (int off = 32; off > 0; off >>= 1) v += __shfl_xor(v, off, 64);
  return v;
}

// ---------------------------------------------------------------------------
// Kernel 0 (fused): ALL input-dependent prep in one launch.
// blocks [0,144): enc conv2 B-frags | [144,208): dec1 frags |
// [208,992): decfc frags | [992,5088): mem frags | [5088,13280): mem norms.
// ---------------------------------------------------------------------------
__global__ __launch_bounds__(64) void prep_all(
    const float* __restrict__ ce_w2, const float* __restrict__ ge_w2,
    const float* __restrict__ d_w1, const float* __restrict__ dfcw,
    const float* __restrict__ memg, float* __restrict__ frags,
    float* __restrict__ dec1frags, float* __restrict__ dfcfrags,
    float* __restrict__ memfrags, float* __restrict__ invn) {
  const int blk = blockIdx.x;
  const int lane = threadIdx.x;

  if (blk < 144) {  // encoder conv2 B-fragments (2-part f16 split)
    const int enc = blk / 72;
    const int frag = blk % 72;
    const int ks = frag >> 2, part = (frag >> 1) & 1, nt = frag & 1;
    const int tap = ks >> 1, half = ks & 1;
    const float* w2 = enc ? ge_w2 : ce_w2;
    const int n = nt * 32 + (lane & 31);
    const int cb = half * 16 + (lane >> 5) * 8;
    half8 out;
#pragma unroll
    for (int j = 0; j < 8; ++j) {
      float v = w2[(n * 32 + cb + j) * 9 + tap];
      _Float16 h = (_Float16)v;
      out[j] = (part == 0) ? h : (_Float16)((v - (float)h) * 4096.f);
    }
    *(half8*)((char*)frags + ((size_t)blk * 64 + lane) * 16) = out;
  } else if (blk < 208) {  // decoder deconv1 B-fragments
    const int b2 = blk - 144;
    const int phase = b2 >> 4, ks = b2 & 15;
    const int pa = phase >> 1, pb = phase & 1;
    const int st = ks >> 2, kk = ks & 3;
    const int s = st >> 1, tt = st & 1;
    const int kg = lane >> 5, n = lane & 31;
    const int tap = (pa + 2 * s) * 4 + (pb + 2 * tt);
    half8 o;
#pragma unroll
    for (int j = 0; j < 8; ++j) {
      int c = kk * 16 + kg * 8 + j;
      o[j] = (_Float16)d_w1[tap * 2048 + c * 32 + n];
    }
    *(half8*)((char*)dec1frags + ((size_t)b2 * 64 + lane) * 16) = o;
  } else if (blk < 992) {  // decfc B-fragments
    const int b2 = blk - 208;
    const int nt = b2 >> 3, ks = b2 & 7;
    const int n = lane & 31, kg = lane >> 5;
    const int j = nt * 32 + n;
    const int px = j >> 6, c = j & 63;
    half8 o;
#pragma unroll
    for (int u = 0; u < 8; ++u)
      o[u] = (_Float16)dfcw[(size_t)(c * 49 + px) * 128 + ks * 16 + kg * 8 + u];
    *(half8*)((char*)dfcfrags + ((size_t)b2 * 64 + lane) * 16) = o;
  } else if (blk < 5088) {  // mem B-fragments (2-part split)
    const int b2 = blk - 992;
    const int slot = b2 & 15;
    const int p = slot >> 3, ks = slot & 7;
    const int T = b2 >> 4;
    const int n = lane & 31, kg = lane >> 5;
    const float* src = memg + (size_t)(T * 32 + n) * 128 + ks * 16 + kg * 8;
    half8 o;
#pragma unroll
    for (int j = 0; j < 8; ++j) {
      float v = src[j];
      _Float16 h = (_Float16)v;
      o[j] = p ? (_Float16)((v - (float)h) * 4096.f) : h;
    }
    *(half8*)((char*)memfrags + ((size_t)b2 * 64 + lane) * 16) = o;
  } else {  // mem row inverse norms (1 row per 64-thread block)
    const int row = blk - 5088;
    const float* r = memg + (size_t)row * 128;
    float a = r[lane], b = r[lane + 64];
    float s = wave_reduce_sum(a * a + b * b);
    if (lane == 0) invn[row] = 1.f / fmaxf(sqrtf(s), 1e-12f);
  }
}

// ---------------------------------------------------------------------------
// Kernel 2: MFMA encoder (v4 — proven 308us, no spill).
// Bands of 7 rows (uniform), 4 blocks/CU, MFMA unit = (M-tile, both nt).
// NOTE: unified VGPR+AGPR file: 64 arch + 64 acc = exactly the 128/wave cap
// at (256,4). Any added register pressure spills catastrophically
// (v6: 2.6GB, v7: 2.2GB scratch). Do not pipeline this loop at source level.
// ---------------------------------------------------------------------------
template <int S, bool CENTER>
__device__ __forceinline__ void encoder_body(
    char* smem, const float* __restrict__ x, const float* __restrict__ w1,
    const float* __restrict__ b1, const float* __restrict__ b2,
    const float* __restrict__ fcw, const float* __restrict__ fcb,
    const float* __restrict__ bfrag, float* __restrict__ zout, int zoff,
    int b) {
  constexpr int SP = S + 2;
  constexpr int NBANDS = S / 7;
  constexpr int NPIX = 9 * SP;
  constexpr int GSTB = NPIX * 16;
  constexpr int PSTB = 4 * GSTB;
  constexpr int LIMIT = 7 * S;
  constexpr int MTB = (LIMIT + 31) / 32;

  char* h1s = smem;
  float* xs = (float*)(smem + 2 * PSTB);
  float* w1s = xs + SP * SP;
  float* featp = w1s + 288;  // [4][64]

  const int t = threadIdx.x;
  const int lane = t & 63;
  const int wv = t >> 6;

  for (int e = t; e < SP * SP; e += TPB) xs[e] = 0.f;
  for (int e = t; e < 288; e += TPB) w1s[e] = w1[e];
  __syncthreads();
  const float* xb = x + (size_t)b * 784 + (CENTER ? (7 * 28 + 7) : 0);
  for (int e = t; e < S * S; e += TPB) {
    int i = e / S, j = e - i * S;
    xs[(i + 1) * SP + (j + 1)] = xb[i * 28 + j];
  }

  float sp0 = 0.f, sp1 = 0.f;
  const float bias0 = b2[lane & 31];
  const float bias1 = b2[32 + (lane & 31)];
  const int gOff = (lane >> 5) * GSTB;
  const char* bgbase = (const char*)bfrag + lane * 16;

#pragma unroll 1
  for (int band = 0; band < NBANDS; ++band) {
    const int b0 = band * 7;

    __syncthreads();
    for (int e = t; e < 4 * NPIX; e += TPB) {
      int g = e / NPIX;
      int pix = e - g * NPIX;
      int lr = pix / SP;
      int cw = pix - lr * SP;
      int gr = b0 - 1 + lr;
      int ebase = g * GSTB + pix * 16;
      half8 hi8 = {}, lo8 = {};
      if (gr >= 0 && gr < S && cw >= 1 && cw <= S) {
        float xv[9];
#pragma unroll
        for (int di = 0; di < 3; ++di)
#pragma unroll
          for (int dj = 0; dj < 3; ++dj)
            xv[di * 3 + dj] = xs[(gr + di) * SP + (cw - 1 + dj)];
#pragma unroll
        for (int u = 0; u < 8; ++u) {
          int ch = g * 8 + u;
          float a = b1[ch];
#pragma unroll
          for (int v = 0; v < 9; ++v) a += xv[v] * w1s[ch * 9 + v];
          a = fmaxf(a, 0.f);
          _Float16 h = (_Float16)a;
          hi8[u] = h;
          lo8[u] = (_Float16)((a - (float)h) * 4096.f);
        }
      }
      *(half8*)(h1s + ebase) = hi8;
      *(half8*)(h1s + PSTB + ebase) = lo8;
    }
    __syncthreads();
#pragma unroll 1
    for (int mt = wv; mt < MTB; mt += 4) {
      floatx16 aH0 = {}, aL0 = {}, aH1 = {}, aL1 = {};
      int px = mt * 32 + (lane & 31);
      px = px < LIMIT ? px : LIMIT - 1;
      const int r = px / S, cc = px - r * S;
      const int pixB = (r * SP + cc) * 16;
#pragma unroll 3
      for (int tap = 0; tap < 9; ++tap) {
        const int di = tap / 3, dj = tap - di * 3;
        const int offT = (di * SP + dj) * 16;
#pragma unroll
        for (int half = 0; half < 2; ++half) {
          const int ks = tap * 2 + half;
          const char* bp = bgbase + ks * 4096;
          const int offA = pixB + offT + gOff + half * (2 * GSTB);
          half8 ah = *(const half8*)(h1s + offA);
          half8 al = *(const half8*)(h1s + PSTB + offA);
          {  // nt = 0
            half8 bh = *(const half8*)(bp);
            half8 bl = *(const half8*)(bp + 2048);
            aH0 = __builtin_amdgcn_mfma_f32_32x32x16_f16(ah, bh, aH0, 0, 0, 0);
            aL0 = __builtin_amdgcn_mfma_f32_32x32x16_f16(ah, bl, aL0, 0, 0, 0);
            aL0 = __builtin_amdgcn_mfma_f32_32x32x16_f16(al, bh, aL0, 0, 0, 0);
          }
          {  // nt = 1
            half8 bh = *(const half8*)(bp + 1024);
            half8 bl = *(const half8*)(bp + 3072);
            aH1 = __builtin_amdgcn_mfma_f32_32x32x16_f16(ah, bh, aH1, 0, 0, 0);
            aL1 = __builtin_amdgcn_mfma_f32_32x32x16_f16(ah, bl, aL1, 0, 0, 0);
            aL1 = __builtin_amdgcn_mfma_f32_32x32x16_f16(al, bh, aL1, 0, 0, 0);
          }
        }
      }
#pragma unroll
      for (int reg = 0; reg < 16; ++reg) {
        int row = (reg & 3) + 8 * (reg >> 2) + 4 * (lane >> 5);
        int p = mt * 32 + row;
        if (p < LIMIT) {
          sp0 += fmaxf(aH0[reg] + aL0[reg] * (1.f / 4096.f) + bias0, 0.f);
          sp1 += fmaxf(aH1[reg] + aL1[reg] * (1.f / 4096.f) + bias1, 0.f);
        }
      }
    }
  }
  sp0 += __shfl_xor(sp0, 32);
  sp1 += __shfl_xor(sp1, 32);
  if (lane < 32) {
    featp[wv * 64 + lane] = sp0;
    featp[wv * 64 + 32 + lane] = sp1;
  }
  __syncthreads();
  if (t < 64)
    featp[t] = (featp[t] + featp[64 + t] + featp[128 + t] + featp[192 + t]) *
               (1.f / (S * S));
  __syncthreads();
  if (t < 64) {
    float s = 0.f;
#pragma unroll
    for (int i = 0; i < 64; ++i) s += featp[i] * fcw[t * 64 + i];
    zout[(size_t)b * 128 + zoff + t] = s + fcb[t];
  }
}

__global__ __launch_bounds__(256, 4) void encoders_fused(
    const float* __restrict__ x, const float* __restrict__ ce_w1,
    const float* __restrict__ ce_b1, const float* __restrict__ ce_b2,
    const float* __restrict__ ce_fcw, const float* __restrict__ ce_fcb,
    const float* __restrict__ ge_w1, const float* __restrict__ ge_b1,
    const float* __restrict__ ge_b2, const float* __restrict__ ge_fcw,
    const float* __restrict__ ge_fcb, const float* __restrict__ frags,
    float* __restrict__ z) {
  // S=28: 2*PSTB(34560) + xs(3600) + w1s(1152) + featp(1024) = 40336 -> 4/CU
  __shared__ __align__(16) char smem[40336];
  if (blockIdx.x < 2048)
    encoder_body<28, false>(smem, x, ge_w1, ge_b1, ge_b2, ge_fcw, ge_fcb,
                            frags + 18432, z, 64, blockIdx.x);
  else
    encoder_body<14, true>(smem, x, ce_w1, ce_b1, ce_b2, ce_fcw, ce_fcb, frags,
                           z, 0, blockIdx.x - 2048);
}

// ---------------------------------------------------------------------------
// Kernel 2b: z normalize + A-fragment build, once per 32-row z-block.
// ---------------------------------------------------------------------------
__global__ __launch_bounds__(256) void zprep_kernel(
    const float* __restrict__ z, float* __restrict__ zfragg) {
  __shared__ __align__(16) float zs[4096];
  __shared__ __align__(16) char zfrag[16384];
  const int t = threadIdx.x;
  const int lane = t & 63;
  const int wv = t >> 6;
  const int rowbase = blockIdx.x * 32;

  for (int e = t; e < 4096; e += TPB) zs[e] = z[(size_t)rowbase * 128 + e];
  __syncthreads();
#pragma unroll
  for (int h = 0; h < 8; ++h) {
    int r = wv * 8 + h;
    float a = zs[r * 128 + lane], b = zs[r * 128 + 64 + lane];
    float s = wave_reduce_sum(a * a + b * b);
    float inv = 1.f / fmaxf(sqrtf(s), 1e-12f);
    zs[r * 128 + lane] = a * inv;
    zs[r * 128 + 64 + lane] = b * inv;
  }
  __syncthreads();
  for (int e = t; e < 4096; e += TPB) {
    int m = e >> 7, c = e & 127;
    float v = zs[m * 128 + c];
    _Float16 h = (_Float16)v;
    _Float16 l = (_Float16)((v - (float)h) * 4096.f);
    int ks = c >> 4, kg = (c >> 3) & 1, j = c & 7;
    int off = (ks * 64 + kg * 32 + m) * 16 + j * 2;
    *(_Float16*)(zfrag + off) = h;
    *(_Float16*)(zfrag + 8192 + off) = l;
  }
  __syncthreads();
  const float4* src = (const float4*)zfrag;
  float4* dst = (float4*)(zfragg + (size_t)blockIdx.x * 4096);
  for (int e = t; e < 1024; e += TPB) dst[e] = src[e];
}

// ---------------------------------------------------------------------------
// Kernel 3a: match via split-f16 MFMA (A-frags from precomputed zfragg).
// ---------------------------------------------------------------------------
__global__ __launch_bounds__(256) void match_mfma(
    const float* __restrict__ zfragg, const float* __restrict__ memfrags,
    const float* __restrict__ invn, float* __restrict__ topvw,
    int* __restrict__ topiw) {
  __shared__ __align__(16) char smem[33024];
  float* qv = (float*)smem;            // [32][128]
  int* qi = (int*)(smem + 16384);      // [32][128]
  float* rowmin = (float*)(smem + 32768);
  int* qn = (int*)(smem + 32768 + 128);

  const int t = threadIdx.x;
  const int lane = t & 63;
  const int wv = t >> 6;
  const int rowbase = blockIdx.x * 32;
  const int Tbase = blockIdx.y * 16;

  if (t < 32) { rowmin[t] = -FLT_MAX; qn[t] = 0; }

  half8 ah[8], al[8];
  {
    const char* zf = (const char*)zfragg + (size_t)blockIdx.x * 16384 +
                     ((lane >> 5) * 32 + (lane & 31)) * 16;
#pragma unroll
    for (int ks = 0; ks < 8; ++ks) {
      ah[ks] = *(const half8*)(zf + ks * 1024);
      al[ks] = *(const half8*)(zf + 8192 + ks * 1024);
    }
  }
  __syncthreads();

  float av[10];
  int ai[10];
#pragma unroll
  for (int i = 0; i < 10; ++i) { av[i] = -FLT_MAX; ai[i] = 0; }

#pragma unroll 1
  for (int round = 0; round < 4; ++round) {
    const int T = Tbase + round * 4 + wv;
    const char* bf = (const char*)memfrags + (size_t)T * 16384 + lane * 16;
    floatx16 acc0 = {}, acc1 = {};
#pragma unroll
    for (int ks = 0; ks < 8; ++ks) {
      half8 bh = *(const half8*)(bf + ks * 1024);
      half8 bl = *(const half8*)(bf + 8192 + ks * 1024);
      acc0 = __builtin_amdgcn_mfma_f32_32x32x16_f16(ah[ks], bh, acc0, 0, 0, 0);
      acc1 = __builtin_amdgcn_mfma_f32_32x32x16_f16(ah[ks], bl, acc1, 0, 0, 0);
      acc1 = __builtin_amdgcn_mfma_f32_32x32x16_f16(al[ks], bh, acc1, 0, 0, 0);
    }
    const int gn = T * 32 + (lane & 31);
    const float iv = invn[gn];
#pragma unroll
    for (int reg = 0; reg < 16; ++reg) {
      int m = (reg & 3) + 8 * (reg >> 2) + 4 * (lane >> 5);
      float v = (acc0[reg] + acc1[reg] * (1.f / 4096.f)) * iv;
      if (v > rowmin[m]) {
        int k = atomicAdd(&qn[m], 1);
        qv[m * 128 + k] = v;
        qi[m * 128 + k] = gn;
      }
    }
    __syncthreads();
    if (t < 32) {
      int n = qn[t];
      for (int k = 0; k < n; ++k) {
        float v = qv[t * 128 + k];
        int mm = qi[t * 128 + k];
        if (v > av[9]) {
#pragma unroll
          for (int i = 0; i < 10; ++i) {
            if (v > av[i]) {
              float tv = av[i]; av[i] = v; v = tv;
              int ti = ai[i]; ai[i] = mm; mm = ti;
            }
          }
        }
      }
      qn[t] = 0;
      rowmin[t] = av[9];
    }
    __syncthreads();
  }

  if (t < 32) {
    const size_t base = (size_t)(rowbase + t) * 160 + blockIdx.y * 10;
#pragma unroll
    for (int k = 0; k < 10; ++k) {
      topvw[base + k] = av[k];
      topiw[base + k] = ai[k];
    }
  }
}

// ---------------------------------------------------------------------------
// Kernel 3b: merge 16x10 candidates -> exact top-10 -> softmax -> blend (f16).
// ---------------------------------------------------------------------------
__global__ __launch_bounds__(256) void match_merge(
    const float* __restrict__ topvw, const int* __restrict__ topiw,
    const float* __restrict__ memg, _Float16* __restrict__ zmf16) {
  __shared__ float topw[8][10];
  __shared__ int topidx[8][10];
  const int t = threadIdx.x;
  const int rowbase = blockIdx.x * 8;

  if (t < 8) {
    float av[10];
    int ai[10];
#pragma unroll
    for (int i = 0; i < 10; ++i) { av[i] = -FLT_MAX; ai[i] = 0; }
    const size_t base = (size_t)(rowbase + t) * 160;
    for (int c = 0; c < 160; ++c) {
      float v = topvw[base + c];
      int m = topiw[base + c];
      if (v > av[9]) {
#pragma unroll
        for (int i = 0; i < 10; ++i) {
          if (v > av[i]) {
            float tv = av[i]; av[i] = v; v = tv;
            int ti = ai[i]; ai[i] = m; m = ti;
          }
        }
      }
    }
    float e_[10], s = 0.f;
#pragma unroll
    for (int k = 0; k < 10; ++k) { e_[k] = expf(av[k]); s += e_[k]; }
    float inv = 1.f / s;
#pragma unroll
    for (int k = 0; k < 10; ++k) { topw[t][k] = e_[k] * inv; topidx[t][k] = ai[k]; }
  }
  __syncthreads();
  for (int e = t; e < 8 * 128; e += TPB) {
    int r = e >> 7, d = e & 127;
    float o = 0.f;
#pragma unroll
    for (int k = 0; k < 10; ++k)
      o += topw[r][k] * memg[(size_t)topidx[r][k] * 128 + d];
    zmf16[(size_t)(rowbase + r) * 128 + d] = (_Float16)o;
  }
}

// ---------------------------------------------------------------------------
// Kernel 4: decoder FC via f16 MFMA. v9: grid (64,7) = 448 blocks (was 128 —
// half the GPU idle). ntbase = y*14.
// ---------------------------------------------------------------------------
__global__ __launch_bounds__(256) void decfc_kernel(
    const _Float16* __restrict__ zmf16, const float* __restrict__ fcb,
    const float* __restrict__ dfcfrags, _Float16* __restrict__ d0f16) {
  const int t = threadIdx.x;
  const int lane = t & 63;
  const int wv = t >> 6;
  const int r0 = blockIdx.x * 32;
  const int ntbase = blockIdx.y * 14;

  half8 a[8];
  {
    const _Float16* ap =
        zmf16 + (size_t)(r0 + (lane & 31)) * 128 + (lane >> 5) * 8;
#pragma unroll
    for (int ks = 0; ks < 8; ++ks) a[ks] = *(const half8*)(ap + ks * 16);
  }
  const char* fb = (const char*)dfcfrags + lane * 16;

  for (int nt = ntbase + wv; nt < ntbase + 14; nt += 4) {
    half8 bfr[8];
    const char* p = fb + (size_t)nt * 8192;
#pragma unroll
    for (int ks = 0; ks < 8; ++ks) bfr[ks] = *(const half8*)(p + ks * 1024);
    floatx16 acc = {};
#pragma unroll
    for (int ks = 0; ks < 8; ++ks)
      acc = __builtin_amdgcn_mfma_f32_32x32x16_f16(a[ks], bfr[ks], acc, 0, 0, 0);
    const int col = nt * 32 + (lane & 31);
    const int px = col >> 6, c = col & 63;
    const float bias = fcb[c * 49 + px];
#pragma unroll
    for (int reg = 0; reg < 16; ++reg) {
      int row = (reg & 3) + 8 * (reg >> 2) + 4 * (lane >> 5);
      d0f16[((size_t)(r0 + row) * 49 + px) * 64 + c] = (_Float16)(acc[reg] + bias);
    }
  }
}

// ---------------------------------------------------------------------------
// Kernel 5: decoder — deconv1 + conv2 via f16 MFMA. v9: d3 trimmed to
// 28x30/channel (row halo -> guard in final conv): LDS 41408 -> 39488
// (<=40960 -> 4 blocks/CU possible).
// ---------------------------------------------------------------------------
__global__ __launch_bounds__(256) void decoder_kernel(
    const _Float16* __restrict__ d0f16, const float* __restrict__ b1,
    const float* __restrict__ w2, const float* __restrict__ b2,
    const float* __restrict__ w3, const float* __restrict__ b3,
    const float* __restrict__ w4, const float* __restrict__ b4,
    const float* __restrict__ dec1frags, float* __restrict__ out) {
  __shared__ __align__(16) char dsm[39488];
  char* d0f = dsm;
  float* d2 = (float*)dsm;
  char* d1f = dsm + 12608;
  char* w2s = dsm + 28992;
  float* d3 = (float*)(dsm + 12608);  // [8][28*30] = 26880 B, ends 39488

  const int b = blockIdx.x;
  const int t = threadIdx.x;
  const int lane = t & 63;
  const int wv = t >> 6;

  for (int e = t; e < 648; e += TPB) {
    int g = e / 81, pix = e - g * 81;
    int ih = pix / 9 - 1, iw = pix % 9 - 1;
    half8 hv = {};
    if (ih >= 0 && ih < 7 && iw >= 0 && iw < 7)
      hv = *(const half8*)(d0f16 + ((size_t)b * 49 + ih * 7 + iw) * 64 + g * 8);
    *(half8*)(d0f + e * 16) = hv;
  }
  for (int e = t; e < 576; e += TPB) {
    int tau = e / 64, l = e - tau * 64;
    int n = l & 15, kq = l >> 4;
    half8 v;
#pragma unroll
    for (int u = 0; u < 8; ++u)
      v[u] = (_Float16)w2[(n * 32 + kq * 8 + u) * 9 + tau];
    *(half8*)(w2s + e * 16) = v;
  }
  for (int e = t; e < 1024; e += TPB)
    *(float4*)(d1f + e * 16) = make_float4(0.f, 0.f, 0.f, 0.f);
  __syncthreads();

  {
    const int pa = wv >> 1, pb = wv & 1;
    const int kg = lane >> 5, o = lane & 31;
    const char* bg = (const char*)dec1frags + wv * 16384 + lane * 16;
    int pxa[2][4];
#pragma unroll
    for (int im = 0; im < 2; ++im) {
      int px = im * 32 + o;
      px = px < 49 ? px : 48;
      int i = px / 7, j2 = px - i * 7;
#pragma unroll
      for (int st = 0; st < 4; ++st) {
        int s = st >> 1, tt = st & 1;
        pxa[im][st] = ((i + pa + s) * 9 + (j2 + pb + tt)) * 16;
      }
    }
    floatx16 acc0 = {}, acc1 = {};
    half8 nb = *(const half8*)(bg);
#pragma unroll
    for (int ks = 0; ks < 16; ++ks) {
      half8 bf = nb;
      if (ks < 15) nb = *(const half8*)(bg + (ks + 1) * 1024);
      const int gbase = (((ks & 3) * 2 + kg) * 81) * 16;
      half8 a0 = *(const half8*)(d0f + gbase + pxa[0][ks >> 2]);
      half8 a1 = *(const half8*)(d0f + gbase + pxa[1][ks >> 2]);
      acc0 = __builtin_amdgcn_mfma_f32_32x32x16_f16(a0, bf, acc0, 0, 0, 0);
      acc1 = __builtin_amdgcn_mfma_f32_32x32x16_f16(a1, bf, acc1, 0, 0, 0);
    }
    const float bias = b1[o];
    char* dst = d1f + (o >> 3) * 4096 + (o & 7) * 2;
#pragma unroll
    for (int im = 0; im < 2; ++im) {
      const floatx16& ac = im ? acc1 : acc0;
#pragma unroll
      for (int reg = 0; reg < 16; ++reg) {
        int row = (reg & 3) + 8 * (reg >> 2) + 4 * kg;
        int px = im * 32 + row;
        if (px < 49) {
          int i = px / 7, j2 = px - i * 7;
          int p = 2 * i + pa, q = 2 * j2 + pb;
          *(_Float16*)(dst + ((p + 1) * 16 + (q + 1)) * 16) =
              (_Float16)fmaxf(ac[reg] + bias, 0.f);
        }
      }
    }
  }
  __syncthreads();

  {
    const int m = lane & 15, kq = lane >> 4;
    half8 bq[9];
#pragma unroll
    for (int tau = 0; tau < 9; ++tau)
      bq[tau] = *(const half8*)(w2s + (tau * 64 + lane) * 16);
    for (int mt = wv; mt < 13; mt += 4) {
      int px = mt * 16 + m;
      px = px < 196 ? px : 195;
      const int p = px / 14, q = px - (px / 14) * 14;
      floatx4 acc = {};
#pragma unroll
      for (int tau = 0; tau < 9; ++tau) {
        const int dp = tau / 3, dq = tau - dp * 3;
        half8 av =
            *(const half8*)(d1f + (kq * 256 + (p + dp) * 16 + (q + dq)) * 16);
        acc = __builtin_amdgcn_mfma_f32_16x16x32_f16(av, bq[tau], acc, 0, 0, 0);
      }
      const int o = lane & 15;
      const float bias = b2[o];
#pragma unroll
      for (int reg = 0; reg < 4; ++reg) {
        int row = (lane >> 4) * 4 + reg;
        int opx = mt * 16 + row;
        if (opx < 196) d2[o * 197 + opx] = fmaxf(acc[reg] + bias, 0.f);
      }
    }
  }
  __syncthreads();
  for (int e = t; e < 6720; e += TPB) d3[e] = 0.f;
  __syncthreads();

  {
    const int ph = __builtin_amdgcn_readfirstlane(t >> 6);
    const int pa = ph >> 1, pb = ph & 1;
    const int tb = pa * 4 + pb;
    const float* wA = w3 + (size_t)tb * 128;
    const float* wB = w3 + (size_t)(tb + 2) * 128;
    const float* wC = w3 + (size_t)(tb + 8) * 128;
    const float* wD = w3 + (size_t)(tb + 10) * 128;
#pragma unroll 1
    for (int k = 0; k < 4; ++k) {
      const int px = lane + 64 * k;
      const int cpx = px < 196 ? px : 195;
      const int i = cpx / 14, j = cpx % 14;
      int ih[2], iw[2];
      float mh[2], mw[2];
#pragma unroll
      for (int s = 0; s < 2; ++s) {
        int v = i + pa + s - 1;
        mh[s] = (v >= 0 && v <= 13) ? 1.f : 0.f;
        ih[s] = v < 0 ? 0 : (v > 13 ? 13 : v);
        int u = j + pb + s - 1;
        mw[s] = (u >= 0 && u <= 13) ? 1.f : 0.f;
        iw[s] = u < 0 ? 0 : (u > 13 ? 13 : u);
      }
      const float m00 = mh[0] * mw[0], m01 = mh[0] * mw[1];
      const float m10 = mh[1] * mw[0], m11 = mh[1] * mw[1];
      float acc[8];
#pragma unroll
      for (int oo = 0; oo < 8; ++oo) acc[oo] = b3[oo];
#pragma unroll 2
      for (int c = 0; c < 16; ++c) {
        const float a00 = d2[c * 197 + ih[0] * 14 + iw[0]] * m00;
        const float a01 = d2[c * 197 + ih[0] * 14 + iw[1]] * m01;
        const float a10 = d2[c * 197 + ih[1] * 14 + iw[0]] * m10;
        const float a11 = d2[c * 197 + ih[1] * 14 + iw[1]] * m11;
        const int wb = c * 8;
#pragma unroll
        for (int oo = 0; oo < 8; ++oo)
          acc[oo] += a00 * wA[wb + oo] + a01 * wB[wb + oo] +
                     a10 * wC[wb + oo] + a11 * wD[wb + oo];
      }
      if (px < 196) {
        // d3: [8][28 rows][30 cols], col halo kept (cols 0,29 zero), no row halo
        const int p = 2 * i + pa, q = 2 * j + pb;
        const int widx = p * 30 + (q + 1);
#pragma unroll
        for (int oo = 0; oo < 8; ++oo)
          d3[oo * 840 + widx] = fmaxf(acc[oo], 0.f);
      }
    }
  }
  __syncthreads();

  for (int e = t; e < 784; e += TPB) {
    int p = e / 28, q = e - p * 28;
    float a = b4[0];
#pragma unroll
    for (int di = 0; di < 3; ++di) {
      const int rr = p + di - 1;
      if (rr >= 0 && rr < 28) {
#pragma unroll
        for (int c = 0; c < 8; ++c) {
          const float* bp = &d3[c * 840 + rr * 30 + q];
#pragma unroll
          for (int dj = 0; dj < 3; ++dj)
            a += bp[dj] * w4[c * 9 + di * 3 + dj];
        }
      }
    }
    out[(size_t)b * 784 + e] = a;
  }
}

// ---------------------------------------------------------------------------
extern "C" void kernel_launch(void* const* d_in, const int* in_sizes, int n_in,
                              void* d_out, int out_size, void* d_ws,
                              size_t ws_size, hipStream_t stream) {
  const float* x      = (const float*)d_in[0];
  const float* ce_w1  = (const float*)d_in[1];
  const float* ce_b1  = (const float*)d_in[2];
  const float* ce_w2  = (const float*)d_in[3];
  const float* ce_b2  = (const float*)d_in[4];
  const float* ce_fcw = (const float*)d_in[5];
  const float* ce_fcb = (const float*)d_in[6];
  const float* ge_w1  = (const float*)d_in[7];
  const float* ge_b1  = (const float*)d_in[8];
  const float* ge_w2  = (const float*)d_in[9];
  const float* ge_b2  = (const float*)d_in[10];
  const float* ge_fcw = (const float*)d_in[11];
  const float* ge_fcb = (const float*)d_in[12];
  const float* memg   = (const float*)d_in[13];
  const float* dfcw   = (const float*)d_in[14];
  const float* dfcb   = (const float*)d_in[15];
  const float* d_w1   = (const float*)d_in[16];
  const float* d_b1   = (const float*)d_in[17];
  const float* d_w2   = (const float*)d_in[18];
  const float* d_b2   = (const float*)d_in[19];
  const float* d_w3   = (const float*)d_in[20];
  const float* d_b3   = (const float*)d_in[21];
  const float* d_w4   = (const float*)d_in[22];
  const float* d_b4   = (const float*)d_in[23];
  float* outp = (float*)d_out;

  float*     ws        = (float*)d_ws;
  float*     z         = ws;
  _Float16*  zmf16     = (_Float16*)(ws + 262144);
  float*     invn      = ws + 262144 + 131072;
  float*     frags     = invn + 8192;
  float*     dec1frags = frags + 36864;
  float*     dfcfrags  = dec1frags + 16384;
  float*     memfrags  = dfcfrags + 200704;
  float*     tailbase  = memfrags + 1048576;
  float*     topvw     = tailbase;
  int*       topiw     = (int*)(tailbase + 327680);
  float*     zfragg    = tailbase + 655360;
  _Float16*  d0f16     = (_Float16*)tailbase;

  prep_all<<<13280, 64, 0, stream>>>(ce_w2, ge_w2, d_w1, dfcw, memg, frags,
                                     dec1frags, dfcfrags, memfrags, invn);
  encoders_fused<<<4096, TPB, 0, stream>>>(x, ce_w1, ce_b1, ce_b2, ce_fcw,
                                           ce_fcb, ge_w1, ge_b1, ge_b2, ge_fcw,
                                           ge_fcb, frags, z);
  zprep_kernel<<<64, TPB, 0, stream>>>(z, zfragg);
  match_mfma<<<dim3(64, 16), TPB, 0, stream>>>(zfragg, memfrags, invn, topvw,
                                               topiw);
  match_merge<<<256, TPB, 0, stream>>>(topvw, topiw, memg, zmf16);
  decfc_kernel<<<dim3(64, 7), TPB, 0, stream>>>(zmf16, dfcb, dfcfrags, d0f16);
  decoder_kernel<<<2048, TPB, 0, stream>>>(d0f16, d_b1, d_w2, d_b2, d_w3, d_b3,
                                           d_w4, d_b4, dec1frags, outp);
}

// Round 9
// 630.097 us; speedup vs baseline: 3.5057x; 1.0122x over previous
//
#include <hip/hip_runtime.h>
#include <cfloat>
#include <cmath>

#define TPB 256

typedef _Float16 half8 __attribute__((ext_vector_type(8)));
typedef float floatx16 __attribute__((ext_vector_type(16)));
typedef float floatx4 __attribute__((ext_vector_type(4)));
typedef float floatx2 __attribute__((ext_vector_type(2)));

__device__ __forceinline__ float wave_reduce_sum(float v) {
#pragma unroll
  for (int off = 32; off > 0; off >>= 1) v += __shfl_xor(v, off, 64);
  return v;
}

// ---------------------------------------------------------------------------
// Kernel 0 (fused): ALL input-dependent prep in one launch.
// blocks [0,144): enc conv2 B-frags | [144,208): dec1 frags |
// [208,992): decfc frags | [992,5088): mem frags | [5088,13280): mem norms.
// ---------------------------------------------------------------------------
__global__ __launch_bounds__(64) void prep_all(
    const float* __restrict__ ce_w2, const float* __restrict__ ge_w2,
    const float* __restrict__ d_w1, const float* __restrict__ dfcw,
    const float* __restrict__ memg, float* __restrict__ frags,
    float* __restrict__ dec1frags, float* __restrict__ dfcfrags,
    float* __restrict__ memfrags, float* __restrict__ invn) {
  const int blk = blockIdx.x;
  const int lane = threadIdx.x;

  if (blk < 144) {  // encoder conv2 B-fragments (2-part f16 split)
    const int enc = blk / 72;
    const int frag = blk % 72;
    const int ks = frag >> 2, part = (frag >> 1) & 1, nt = frag & 1;
    const int tap = ks >> 1, half = ks & 1;
    const float* w2 = enc ? ge_w2 : ce_w2;
    const int n = nt * 32 + (lane & 31);
    const int cb = half * 16 + (lane >> 5) * 8;
    half8 out;
#pragma unroll
    for (int j = 0; j < 8; ++j) {
      float v = w2[(n * 32 + cb + j) * 9 + tap];
      _Float16 h = (_Float16)v;
      out[j] = (part == 0) ? h : (_Float16)((v - (float)h) * 4096.f);
    }
    *(half8*)((char*)frags + ((size_t)blk * 64 + lane) * 16) = out;
  } else if (blk < 208) {  // decoder deconv1 B-fragments
    const int b2 = blk - 144;
    const int phase = b2 >> 4, ks = b2 & 15;
    const int pa = phase >> 1, pb = phase & 1;
    const int st = ks >> 2, kk = ks & 3;
    const int s = st >> 1, tt = st & 1;
    const int kg = lane >> 5, n = lane & 31;
    const int tap = (pa + 2 * s) * 4 + (pb + 2 * tt);
    half8 o;
#pragma unroll
    for (int j = 0; j < 8; ++j) {
      int c = kk * 16 + kg * 8 + j;
      o[j] = (_Float16)d_w1[tap * 2048 + c * 32 + n];
    }
    *(half8*)((char*)dec1frags + ((size_t)b2 * 64 + lane) * 16) = o;
  } else if (blk < 992) {  // decfc B-fragments
    const int b2 = blk - 208;
    const int nt = b2 >> 3, ks = b2 & 7;
    const int n = lane & 31, kg = lane >> 5;
    const int j = nt * 32 + n;
    const int px = j >> 6, c = j & 63;
    half8 o;
#pragma unroll
    for (int u = 0; u < 8; ++u)
      o[u] = (_Float16)dfcw[(size_t)(c * 49 + px) * 128 + ks * 16 + kg * 8 + u];
    *(half8*)((char*)dfcfrags + ((size_t)b2 * 64 + lane) * 16) = o;
  } else if (blk < 5088) {  // mem B-fragments (2-part split)
    const int b2 = blk - 992;
    const int slot = b2 & 15;
    const int p = slot >> 3, ks = slot & 7;
    const int T = b2 >> 4;
    const int n = lane & 31, kg = lane >> 5;
    const float* src = memg + (size_t)(T * 32 + n) * 128 + ks * 16 + kg * 8;
    half8 o;
#pragma unroll
    for (int j = 0; j < 8; ++j) {
      float v = src[j];
      _Float16 h = (_Float16)v;
      o[j] = p ? (_Float16)((v - (float)h) * 4096.f) : h;
    }
    *(half8*)((char*)memfrags + ((size_t)b2 * 64 + lane) * 16) = o;
  } else {  // mem row inverse norms (1 row per 64-thread block)
    const int row = blk - 5088;
    const float* r = memg + (size_t)row * 128;
    float a = r[lane], b = r[lane + 64];
    float s = wave_reduce_sum(a * a + b * b);
    if (lane == 0) invn[row] = 1.f / fmaxf(sqrtf(s), 1e-12f);
  }
}

// ---------------------------------------------------------------------------
// Kernel 2: MFMA encoder (v4 — proven 308us, no spill).
// Bands of 7 rows (uniform), 4 blocks/CU, MFMA unit = (M-tile, both nt).
// NOTE: unified VGPR+AGPR file: 64 arch + 64 acc = exactly the 128/wave cap
// at (256,4). Any added register pressure spills catastrophically
// (v6: 2.6GB, v7: 2.2GB scratch). Do not pipeline this loop at source level.
// ---------------------------------------------------------------------------
template <int S, bool CENTER>
__device__ __forceinline__ void encoder_body(
    char* smem, const float* __restrict__ x, const float* __restrict__ w1,
    const float* __restrict__ b1, const float* __restrict__ b2,
    const float* __restrict__ fcw, const float* __restrict__ fcb,
    const float* __restrict__ bfrag, float* __restrict__ zout, int zoff,
    int b) {
  constexpr int SP = S + 2;
  constexpr int NBANDS = S / 7;
  constexpr int NPIX = 9 * SP;
  constexpr int GSTB = NPIX * 16;
  constexpr int PSTB = 4 * GSTB;
  constexpr int LIMIT = 7 * S;
  constexpr int MTB = (LIMIT + 31) / 32;

  char* h1s = smem;
  float* xs = (float*)(smem + 2 * PSTB);
  float* w1s = xs + SP * SP;
  float* featp = w1s + 288;  // [4][64]

  const int t = threadIdx.x;
  const int lane = t & 63;
  const int wv = t >> 6;

  for (int e = t; e < SP * SP; e += TPB) xs[e] = 0.f;
  for (int e = t; e < 288; e += TPB) w1s[e] = w1[e];
  __syncthreads();
  const float* xb = x + (size_t)b * 784 + (CENTER ? (7 * 28 + 7) : 0);
  for (int e = t; e < S * S; e += TPB) {
    int i = e / S, j = e - i * S;
    xs[(i + 1) * SP + (j + 1)] = xb[i * 28 + j];
  }

  float sp0 = 0.f, sp1 = 0.f;
  const float bias0 = b2[lane & 31];
  const float bias1 = b2[32 + (lane & 31)];
  const int gOff = (lane >> 5) * GSTB;
  const char* bgbase = (const char*)bfrag + lane * 16;

#pragma unroll 1
  for (int band = 0; band < NBANDS; ++band) {
    const int b0 = band * 7;

    __syncthreads();
    for (int e = t; e < 4 * NPIX; e += TPB) {
      int g = e / NPIX;
      int pix = e - g * NPIX;
      int lr = pix / SP;
      int cw = pix - lr * SP;
      int gr = b0 - 1 + lr;
      int ebase = g * GSTB + pix * 16;
      half8 hi8 = {}, lo8 = {};
      if (gr >= 0 && gr < S && cw >= 1 && cw <= S) {
        float xv[9];
#pragma unroll
        for (int di = 0; di < 3; ++di)
#pragma unroll
          for (int dj = 0; dj < 3; ++dj)
            xv[di * 3 + dj] = xs[(gr + di) * SP + (cw - 1 + dj)];
#pragma unroll
        for (int u = 0; u < 8; ++u) {
          int ch = g * 8 + u;
          float a = b1[ch];
#pragma unroll
          for (int v = 0; v < 9; ++v) a += xv[v] * w1s[ch * 9 + v];
          a = fmaxf(a, 0.f);
          _Float16 h = (_Float16)a;
          hi8[u] = h;
          lo8[u] = (_Float16)((a - (float)h) * 4096.f);
        }
      }
      *(half8*)(h1s + ebase) = hi8;
      *(half8*)(h1s + PSTB + ebase) = lo8;
    }
    __syncthreads();
#pragma unroll 1
    for (int mt = wv; mt < MTB; mt += 4) {
      floatx16 aH0 = {}, aL0 = {}, aH1 = {}, aL1 = {};
      int px = mt * 32 + (lane & 31);
      px = px < LIMIT ? px : LIMIT - 1;
      const int r = px / S, cc = px - r * S;
      const int pixB = (r * SP + cc) * 16;
#pragma unroll 3
      for (int tap = 0; tap < 9; ++tap) {
        const int di = tap / 3, dj = tap - di * 3;
        const int offT = (di * SP + dj) * 16;
#pragma unroll
        for (int half = 0; half < 2; ++half) {
          const int ks = tap * 2 + half;
          const char* bp = bgbase + ks * 4096;
          const int offA = pixB + offT + gOff + half * (2 * GSTB);
          half8 ah = *(const half8*)(h1s + offA);
          half8 al = *(const half8*)(h1s + PSTB + offA);
          {  // nt = 0
            half8 bh = *(const half8*)(bp);
            half8 bl = *(const half8*)(bp + 2048);
            aH0 = __builtin_amdgcn_mfma_f32_32x32x16_f16(ah, bh, aH0, 0, 0, 0);
            aL0 = __builtin_amdgcn_mfma_f32_32x32x16_f16(ah, bl, aL0, 0, 0, 0);
            aL0 = __builtin_amdgcn_mfma_f32_32x32x16_f16(al, bh, aL0, 0, 0, 0);
          }
          {  // nt = 1
            half8 bh = *(const half8*)(bp + 1024);
            half8 bl = *(const half8*)(bp + 3072);
            aH1 = __builtin_amdgcn_mfma_f32_32x32x16_f16(ah, bh, aH1, 0, 0, 0);
            aL1 = __builtin_amdgcn_mfma_f32_32x32x16_f16(ah, bl, aL1, 0, 0, 0);
            aL1 = __builtin_amdgcn_mfma_f32_32x32x16_f16(al, bh, aL1, 0, 0, 0);
          }
        }
      }
#pragma unroll
      for (int reg = 0; reg < 16; ++reg) {
        int row = (reg & 3) + 8 * (reg >> 2) + 4 * (lane >> 5);
        int p = mt * 32 + row;
        if (p < LIMIT) {
          sp0 += fmaxf(aH0[reg] + aL0[reg] * (1.f / 4096.f) + bias0, 0.f);
          sp1 += fmaxf(aH1[reg] + aL1[reg] * (1.f / 4096.f) + bias1, 0.f);
        }
      }
    }
  }
  sp0 += __shfl_xor(sp0, 32);
  sp1 += __shfl_xor(sp1, 32);
  if (lane < 32) {
    featp[wv * 64 + lane] = sp0;
    featp[wv * 64 + 32 + lane] = sp1;
  }
  __syncthreads();
  if (t < 64)
    featp[t] = (featp[t] + featp[64 + t] + featp[128 + t] + featp[192 + t]) *
               (1.f / (S * S));
  __syncthreads();
  if (t < 64) {
    float s = 0.f;
#pragma unroll
    for (int i = 0; i < 64; ++i) s += featp[i] * fcw[t * 64 + i];
    zout[(size_t)b * 128 + zoff + t] = s + fcb[t];
  }
}

__global__ __launch_bounds__(256, 4) void encoders_fused(
    const float* __restrict__ x, const float* __restrict__ ce_w1,
    const float* __restrict__ ce_b1, const float* __restrict__ ce_b2,
    const float* __restrict__ ce_fcw, const float* __restrict__ ce_fcb,
    const float* __restrict__ ge_w1, const float* __restrict__ ge_b1,
    const float* __restrict__ ge_b2, const float* __restrict__ ge_fcw,
    const float* __restrict__ ge_fcb, const float* __restrict__ frags,
    float* __restrict__ z) {
  // S=28: 2*PSTB(34560) + xs(3600) + w1s(1152) + featp(1024) = 40336 -> 4/CU
  __shared__ __align__(16) char smem[40336];
  if (blockIdx.x < 2048)
    encoder_body<28, false>(smem, x, ge_w1, ge_b1, ge_b2, ge_fcw, ge_fcb,
                            frags + 18432, z, 64, blockIdx.x);
  else
    encoder_body<14, true>(smem, x, ce_w1, ce_b1, ce_b2, ce_fcw, ce_fcb, frags,
                           z, 0, blockIdx.x - 2048);
}

// ---------------------------------------------------------------------------
// Kernel 2b: z normalize + A-fragment build, once per 32-row z-block.
// ---------------------------------------------------------------------------
__global__ __launch_bounds__(256) void zprep_kernel(
    const float* __restrict__ z, float* __restrict__ zfragg) {
  __shared__ __align__(16) float zs[4096];
  __shared__ __align__(16) char zfrag[16384];
  const int t = threadIdx.x;
  const int lane = t & 63;
  const int wv = t >> 6;
  const int rowbase = blockIdx.x * 32;

  for (int e = t; e < 4096; e += TPB) zs[e] = z[(size_t)rowbase * 128 + e];
  __syncthreads();
#pragma unroll
  for (int h = 0; h < 8; ++h) {
    int r = wv * 8 + h;
    float a = zs[r * 128 + lane], b = zs[r * 128 + 64 + lane];
    float s = wave_reduce_sum(a * a + b * b);
    float inv = 1.f / fmaxf(sqrtf(s), 1e-12f);
    zs[r * 128 + lane] = a * inv;
    zs[r * 128 + 64 + lane] = b * inv;
  }
  __syncthreads();
  for (int e = t; e < 4096; e += TPB) {
    int m = e >> 7, c = e & 127;
    float v = zs[m * 128 + c];
    _Float16 h = (_Float16)v;
    _Float16 l = (_Float16)((v - (float)h) * 4096.f);
    int ks = c >> 4, kg = (c >> 3) & 1, j = c & 7;
    int off = (ks * 64 + kg * 32 + m) * 16 + j * 2;
    *(_Float16*)(zfrag + off) = h;
    *(_Float16*)(zfrag + 8192 + off) = l;
  }
  __syncthreads();
  const float4* src = (const float4*)zfrag;
  float4* dst = (float4*)(zfragg + (size_t)blockIdx.x * 4096);
  for (int e = t; e < 1024; e += TPB) dst[e] = src[e];
}

// ---------------------------------------------------------------------------
// Kernel 3a: match via split-f16 MFMA. v10: the candidate queue is replaced
// by DETERMINISTIC slots — row m's 128 values per round map bijectively to
// slot wv*32+col, and the memory index is computable as Tbase*32+round*128+k.
// This deletes the round-0 atomic storm (32-way same-address LDS atomicAdd
// x16 regs x4 waves ~16K cyc/block), qi, qn, rowmin. qv stride padded
// 128->129 so the 32-lane serial scan is bank-conflict-free (was 32-way).
// ---------------------------------------------------------------------------
__global__ __launch_bounds__(256) void match_mfma(
    const float* __restrict__ zfragg, const float* __restrict__ memfrags,
    const float* __restrict__ invn, float* __restrict__ topvw,
    int* __restrict__ topiw) {
  __shared__ __align__(16) float qv[32 * 129];  // 16.5 KB

  const int t = threadIdx.x;
  const int lane = t & 63;
  const int wv = t >> 6;
  const int rowbase = blockIdx.x * 32;
  const int Tbase = blockIdx.y * 16;

  half8 ah[8], al[8];
  {
    const char* zf = (const char*)zfragg + (size_t)blockIdx.x * 16384 +
                     ((lane >> 5) * 32 + (lane & 31)) * 16;
#pragma unroll
    for (int ks = 0; ks < 8; ++ks) {
      ah[ks] = *(const half8*)(zf + ks * 1024);
      al[ks] = *(const half8*)(zf + 8192 + ks * 1024);
    }
  }

  float av[10];
  int ai[10];
#pragma unroll
  for (int i = 0; i < 10; ++i) { av[i] = -FLT_MAX; ai[i] = 0; }

#pragma unroll 1
  for (int round = 0; round < 4; ++round) {
    const int T = Tbase + round * 4 + wv;
    const char* bf = (const char*)memfrags + (size_t)T * 16384 + lane * 16;
    floatx16 acc0 = {}, acc1 = {};
#pragma unroll
    for (int ks = 0; ks < 8; ++ks) {
      half8 bh = *(const half8*)(bf + ks * 1024);
      half8 bl = *(const half8*)(bf + 8192 + ks * 1024);
      acc0 = __builtin_amdgcn_mfma_f32_32x32x16_f16(ah[ks], bh, acc0, 0, 0, 0);
      acc1 = __builtin_amdgcn_mfma_f32_32x32x16_f16(ah[ks], bl, acc1, 0, 0, 0);
      acc1 = __builtin_amdgcn_mfma_f32_32x32x16_f16(al[ks], bh, acc1, 0, 0, 0);
    }
    const int gn = T * 32 + (lane & 31);
    const float iv = invn[gn];
    float* qbase = qv + wv * 32 + (lane & 31);
#pragma unroll
    for (int reg = 0; reg < 16; ++reg) {
      int m = (reg & 3) + 8 * (reg >> 2) + 4 * (lane >> 5);
      qbase[m * 129] = (acc0[reg] + acc1[reg] * (1.f / 4096.f)) * iv;
    }
    __syncthreads();
    if (t < 32) {
      const int gbase = Tbase * 32 + round * 128;
      const float* qr = qv + t * 129;
      for (int k = 0; k < 128; ++k) {
        float v = qr[k];
        if (v > av[9]) {
          int mm = gbase + k;
#pragma unroll
          for (int i = 0; i < 10; ++i) {
            if (v > av[i]) {
              float tv = av[i]; av[i] = v; v = tv;
              int ti = ai[i]; ai[i] = mm; mm = ti;
            }
          }
        }
      }
    }
    __syncthreads();
  }

  if (t < 32) {
    const size_t base = (size_t)(rowbase + t) * 160 + blockIdx.y * 10;
#pragma unroll
    for (int k = 0; k < 10; ++k) {
      topvw[base + k] = av[k];
      topiw[base + k] = ai[k];
    }
  }
}

// ---------------------------------------------------------------------------
// Kernel 3b: merge 16x10 candidates -> exact top-10 -> softmax -> blend (f16).
// ---------------------------------------------------------------------------
__global__ __launch_bounds__(256) void match_merge(
    const float* __restrict__ topvw, const int* __restrict__ topiw,
    const float* __restrict__ memg, _Float16* __restrict__ zmf16) {
  __shared__ float topw[8][10];
  __shared__ int topidx[8][10];
  const int t = threadIdx.x;
  const int rowbase = blockIdx.x * 8;

  if (t < 8) {
    float av[10];
    int ai[10];
#pragma unroll
    for (int i = 0; i < 10; ++i) { av[i] = -FLT_MAX; ai[i] = 0; }
    const size_t base = (size_t)(rowbase + t) * 160;
    for (int c = 0; c < 160; ++c) {
      float v = topvw[base + c];
      int m = topiw[base + c];
      if (v > av[9]) {
#pragma unroll
        for (int i = 0; i < 10; ++i) {
          if (v > av[i]) {
            float tv = av[i]; av[i] = v; v = tv;
            int ti = ai[i]; ai[i] = m; m = ti;
          }
        }
      }
    }
    float e_[10], s = 0.f;
#pragma unroll
    for (int k = 0; k < 10; ++k) { e_[k] = expf(av[k]); s += e_[k]; }
    float inv = 1.f / s;
#pragma unroll
    for (int k = 0; k < 10; ++k) { topw[t][k] = e_[k] * inv; topidx[t][k] = ai[k]; }
  }
  __syncthreads();
  for (int e = t; e < 8 * 128; e += TPB) {
    int r = e >> 7, d = e & 127;
    float o = 0.f;
#pragma unroll
    for (int k = 0; k < 10; ++k)
      o += topw[r][k] * memg[(size_t)topidx[r][k] * 128 + d];
    zmf16[(size_t)(rowbase + r) * 128 + d] = (_Float16)o;
  }
}

// ---------------------------------------------------------------------------
// Kernel 4: decoder FC via f16 MFMA. Grid (64,7) = 448 blocks.
// ---------------------------------------------------------------------------
__global__ __launch_bounds__(256) void decfc_kernel(
    const _Float16* __restrict__ zmf16, const float* __restrict__ fcb,
    const float* __restrict__ dfcfrags, _Float16* __restrict__ d0f16) {
  const int t = threadIdx.x;
  const int lane = t & 63;
  const int wv = t >> 6;
  const int r0 = blockIdx.x * 32;
  const int ntbase = blockIdx.y * 14;

  half8 a[8];
  {
    const _Float16* ap =
        zmf16 + (size_t)(r0 + (lane & 31)) * 128 + (lane >> 5) * 8;
#pragma unroll
    for (int ks = 0; ks < 8; ++ks) a[ks] = *(const half8*)(ap + ks * 16);
  }
  const char* fb = (const char*)dfcfrags + lane * 16;

  for (int nt = ntbase + wv; nt < ntbase + 14; nt += 4) {
    half8 bfr[8];
    const char* p = fb + (size_t)nt * 8192;
#pragma unroll
    for (int ks = 0; ks < 8; ++ks) bfr[ks] = *(const half8*)(p + ks * 1024);
    floatx16 acc = {};
#pragma unroll
    for (int ks = 0; ks < 8; ++ks)
      acc = __builtin_amdgcn_mfma_f32_32x32x16_f16(a[ks], bfr[ks], acc, 0, 0, 0);
    const int col = nt * 32 + (lane & 31);
    const int px = col >> 6, c = col & 63;
    const float bias = fcb[c * 49 + px];
#pragma unroll
    for (int reg = 0; reg < 16; ++reg) {
      int row = (reg & 3) + 8 * (reg >> 2) + 4 * (lane >> 5);
      d0f16[((size_t)(r0 + row) * 49 + px) * 64 + c] = (_Float16)(acc[reg] + bias);
    }
  }
}

// ---------------------------------------------------------------------------
// Kernel 5: decoder — deconv1 + conv2 via f16 MFMA. v10: deconv2 (w3) phase
// packed as floatx2 -> v_pk_fma_f32 (halves VALU issue of the heaviest
// scalar phase; same per-element accumulation order, bit-identical).
// ---------------------------------------------------------------------------
__global__ __launch_bounds__(256) void decoder_kernel(
    const _Float16* __restrict__ d0f16, const float* __restrict__ b1,
    const float* __restrict__ w2, const float* __restrict__ b2,
    const float* __restrict__ w3, const float* __restrict__ b3,
    const float* __restrict__ w4, const float* __restrict__ b4,
    const float* __restrict__ dec1frags, float* __restrict__ out) {
  __shared__ __align__(16) char dsm[39488];
  char* d0f = dsm;
  float* d2 = (float*)dsm;
  char* d1f = dsm + 12608;
  char* w2s = dsm + 28992;
  float* d3 = (float*)(dsm + 12608);  // [8][28*30] = 26880 B

  const int b = blockIdx.x;
  const int t = threadIdx.x;
  const int lane = t & 63;
  const int wv = t >> 6;

  for (int e = t; e < 648; e += TPB) {
    int g = e / 81, pix = e - g * 81;
    int ih = pix / 9 - 1, iw = pix % 9 - 1;
    half8 hv = {};
    if (ih >= 0 && ih < 7 && iw >= 0 && iw < 7)
      hv = *(const half8*)(d0f16 + ((size_t)b * 49 + ih * 7 + iw) * 64 + g * 8);
    *(half8*)(d0f + e * 16) = hv;
  }
  for (int e = t; e < 576; e += TPB) {
    int tau = e / 64, l = e - tau * 64;
    int n = l & 15, kq = l >> 4;
    half8 v;
#pragma unroll
    for (int u = 0; u < 8; ++u)
      v[u] = (_Float16)w2[(n * 32 + kq * 8 + u) * 9 + tau];
    *(half8*)(w2s + e * 16) = v;
  }
  for (int e = t; e < 1024; e += TPB)
    *(float4*)(d1f + e * 16) = make_float4(0.f, 0.f, 0.f, 0.f);
  __syncthreads();

  {
    const int pa = wv >> 1, pb = wv & 1;
    const int kg = lane >> 5, o = lane & 31;
    const char* bg = (const char*)dec1frags + wv * 16384 + lane * 16;
    int pxa[2][4];
#pragma unroll
    for (int im = 0; im < 2; ++im) {
      int px = im * 32 + o;
      px = px < 49 ? px : 48;
      int i = px / 7, j2 = px - i * 7;
#pragma unroll
      for (int st = 0; st < 4; ++st) {
        int s = st >> 1, tt = st & 1;
        pxa[im][st] = ((i + pa + s) * 9 + (j2 + pb + tt)) * 16;
      }
    }
    floatx16 acc0 = {}, acc1 = {};
    half8 nb = *(const half8*)(bg);
#pragma unroll
    for (int ks = 0; ks < 16; ++ks) {
      half8 bf = nb;
      if (ks < 15) nb = *(const half8*)(bg + (ks + 1) * 1024);
      const int gbase = (((ks & 3) * 2 + kg) * 81) * 16;
      half8 a0 = *(const half8*)(d0f + gbase + pxa[0][ks >> 2]);
      half8 a1 = *(const half8*)(d0f + gbase + pxa[1][ks >> 2]);
      acc0 = __builtin_amdgcn_mfma_f32_32x32x16_f16(a0, bf, acc0, 0, 0, 0);
      acc1 = __builtin_amdgcn_mfma_f32_32x32x16_f16(a1, bf, acc1, 0, 0, 0);
    }
    const float bias = b1[o];
    char* dst = d1f + (o >> 3) * 4096 + (o & 7) * 2;
#pragma unroll
    for (int im = 0; im < 2; ++im) {
      const floatx16& ac = im ? acc1 : acc0;
#pragma unroll
      for (int reg = 0; reg < 16; ++reg) {
        int row = (reg & 3) + 8 * (reg >> 2) + 4 * kg;
        int px = im * 32 + row;
        if (px < 49) {
          int i = px / 7, j2 = px - i * 7;
          int p = 2 * i + pa, q = 2 * j2 + pb;
          *(_Float16*)(dst + ((p + 1) * 16 + (q + 1)) * 16) =
              (_Float16)fmaxf(ac[reg] + bias, 0.f);
        }
      }
    }
  }
  __syncthreads();

  {
    const int m = lane & 15, kq = lane >> 4;
    half8 bq[9];
#pragma unroll
    for (int tau = 0; tau < 9; ++tau)
      bq[tau] = *(const half8*)(w2s + (tau * 64 + lane) * 16);
    for (int mt = wv; mt < 13; mt += 4) {
      int px = mt * 16 + m;
      px = px < 196 ? px : 195;
      const int p = px / 14, q = px - (px / 14) * 14;
      floatx4 acc = {};
#pragma unroll
      for (int tau = 0; tau < 9; ++tau) {
        const int dp = tau / 3, dq = tau - dp * 3;
        half8 av =
            *(const half8*)(d1f + (kq * 256 + (p + dp) * 16 + (q + dq)) * 16);
        acc = __builtin_amdgcn_mfma_f32_16x16x32_f16(av, bq[tau], acc, 0, 0, 0);
      }
      const int o = lane & 15;
      const float bias = b2[o];
#pragma unroll
      for (int reg = 0; reg < 4; ++reg) {
        int row = (lane >> 4) * 4 + reg;
        int opx = mt * 16 + row;
        if (opx < 196) d2[o * 197 + opx] = fmaxf(acc[reg] + bias, 0.f);
      }
    }
  }
  __syncthreads();
  for (int e = t; e < 6720; e += TPB) d3[e] = 0.f;
  __syncthreads();

  {
    const int ph = __builtin_amdgcn_readfirstlane(t >> 6);
    const int pa = ph >> 1, pb = ph & 1;
    const int tb = pa * 4 + pb;
    const floatx2* wA2 = (const floatx2*)(w3 + (size_t)tb * 128);
    const floatx2* wB2 = (const floatx2*)(w3 + (size_t)(tb + 2) * 128);
    const floatx2* wC2 = (const floatx2*)(w3 + (size_t)(tb + 8) * 128);
    const floatx2* wD2 = (const floatx2*)(w3 + (size_t)(tb + 10) * 128);
#pragma unroll 1
    for (int k = 0; k < 4; ++k) {
      const int px = lane + 64 * k;
      const int cpx = px < 196 ? px : 195;
      const int i = cpx / 14, j = cpx % 14;
      int ih[2], iw[2];
      float mh[2], mw[2];
#pragma unroll
      for (int s = 0; s < 2; ++s) {
        int v = i + pa + s - 1;
        mh[s] = (v >= 0 && v <= 13) ? 1.f : 0.f;
        ih[s] = v < 0 ? 0 : (v > 13 ? 13 : v);
        int u = j + pb + s - 1;
        mw[s] = (u >= 0 && u <= 13) ? 1.f : 0.f;
        iw[s] = u < 0 ? 0 : (u > 13 ? 13 : u);
      }
      const float m00 = mh[0] * mw[0], m01 = mh[0] * mw[1];
      const float m10 = mh[1] * mw[0], m11 = mh[1] * mw[1];
      floatx2 acc2[4];
#pragma unroll
      for (int o2 = 0; o2 < 4; ++o2) {
        acc2[o2][0] = b3[2 * o2];
        acc2[o2][1] = b3[2 * o2 + 1];
      }
#pragma unroll 2
      for (int c = 0; c < 16; ++c) {
        const float a00 = d2[c * 197 + ih[0] * 14 + iw[0]] * m00;
        const float a01 = d2[c * 197 + ih[0] * 14 + iw[1]] * m01;
        const float a10 = d2[c * 197 + ih[1] * 14 + iw[0]] * m10;
        const float a11 = d2[c * 197 + ih[1] * 14 + iw[1]] * m11;
        const int wb2 = c * 4;
#pragma unroll
        for (int o2 = 0; o2 < 4; ++o2)
          acc2[o2] += a00 * wA2[wb2 + o2] + a01 * wB2[wb2 + o2] +
                      a10 * wC2[wb2 + o2] + a11 * wD2[wb2 + o2];
      }
      if (px < 196) {
        // d3: [8][28 rows][30 cols], col halo kept, no row halo
        const int p = 2 * i + pa, q = 2 * j + pb;
        const int widx = p * 30 + (q + 1);
#pragma unroll
        for (int oo = 0; oo < 8; ++oo)
          d3[oo * 840 + widx] = fmaxf(acc2[oo >> 1][oo & 1], 0.f);
      }
    }
  }
  __syncthreads();

  for (int e = t; e < 784; e += TPB) {
    int p = e / 28, q = e - p * 28;
    float a = b4[0];
#pragma unroll
    for (int di = 0; di < 3; ++di) {
      const int rr = p + di - 1;
      if (rr >= 0 && rr < 28) {
#pragma unroll
        for (int c = 0; c < 8; ++c) {
          const float* bp = &d3[c * 840 + rr * 30 + q];
#pragma unroll
          for (int dj = 0; dj < 3; ++dj)
            a += bp[dj] * w4[c * 9 + di * 3 + dj];
        }
      }
    }
    out[(size_t)b * 784 + e] = a;
  }
}

// ---------------------------------------------------------------------------
extern "C" void kernel_launch(void* const* d_in, const int* in_sizes, int n_in,
                              void* d_out, int out_size, void* d_ws,
                              size_t ws_size, hipStream_t stream) {
  const float* x      = (const float*)d_in[0];
  const float* ce_w1  = (const float*)d_in[1];
  const float* ce_b1  = (const float*)d_in[2];
  const float* ce_w2  = (const float*)d_in[3];
  const float* ce_b2  = (const float*)d_in[4];
  const float* ce_fcw = (const float*)d_in[5];
  const float* ce_fcb = (const float*)d_in[6];
  const float* ge_w1  = (const float*)d_in[7];
  const float* ge_b1  = (const float*)d_in[8];
  const float* ge_w2  = (const float*)d_in[9];
  const float* ge_b2  = (const float*)d_in[10];
  const float* ge_fcw = (const float*)d_in[11];
  const float* ge_fcb = (const float*)d_in[12];
  const float* memg   = (const float*)d_in[13];
  const float* dfcw   = (const float*)d_in[14];
  const float* dfcb   = (const float*)d_in[15];
  const float* d_w1   = (const float*)d_in[16];
  const float* d_b1   = (const float*)d_in[17];
  const float* d_w2   = (const float*)d_in[18];
  const float* d_b2   = (const float*)d_in[19];
  const float* d_w3   = (const float*)d_in[20];
  const float* d_b3   = (const float*)d_in[21];
  const float* d_w4   = (const float*)d_in[22];
  const float* d_b4   = (const float*)d_in[23];
  float* outp = (float*)d_out;

  float*     ws        = (float*)d_ws;
  float*     z         = ws;
  _Float16*  zmf16     = (_Float16*)(ws + 262144);
  float*     invn      = ws + 262144 + 131072;
  float*     frags     = invn + 8192;
  float*     dec1frags = frags + 36864;
  float*     dfcfrags  = dec1frags + 16384;
  float*     memfrags  = dfcfrags + 200704;
  float*     tailbase  = memfrags + 1048576;
  float*     topvw     = tailbase;
  int*       topiw     = (int*)(tailbase + 327680);
  float*     zfragg    = tailbase + 655360;
  _Float16*  d0f16     = (_Float16*)tailbase;

  prep_all<<<13280, 64, 0, stream>>>(ce_w2, ge_w2, d_w1, dfcw, memg, frags,
                                     dec1frags, dfcfrags, memfrags, invn);
  encoders_fused<<<4096, TPB, 0, stream>>>(x, ce_w1, ce_b1, ce_b2, ce_fcw,
                                           ce_fcb, ge_w1, ge_b1, ge_b2, ge_fcw,
                                           ge_fcb, frags, z);
  zprep_kernel<<<64, TPB, 0, stream>>>(z, zfragg);
  match_mfma<<<dim3(64, 16), TPB, 0, stream>>>(zfragg, memfrags, invn, topvw,
                                               topiw);
  match_merge<<<256, TPB, 0, stream>>>(topvw, topiw, memg, zmf16);
  decfc_kernel<<<dim3(64, 7), TPB, 0, stream>>>(zmf16, dfcb, dfcfrags, d0f16);
  decoder_kernel<<<2048, TPB, 0, stream>>>(d0f16, d_b1, d_w2, d_b2, d_w3, d_b3,
                                           d_w4, d_b4, dec1frags, outp);
}